// Round 3
// baseline (350.232 us; speedup 1.0000x reference)
//
#include <hip/hip_runtime.h>

#define SEQ  2048
#define EMB  256
#define NH   8
#define HD   32
#define NB   4
#define KTOP 204
#define IDXP 208
#define KPW  52       // keys per wave (4*52 = 208, padded)
#define MBOUND 4e-4f  // top-k margin for fp32 re-verify

typedef unsigned long long ull;
typedef unsigned short u16;

using frag8  = __attribute__((ext_vector_type(8))) short;  // 8 bf16
using f32x4v = __attribute__((ext_vector_type(4))) float;
typedef _Float16 f16;
typedef _Float16 f16x2 __attribute__((ext_vector_type(2)));

union U4 { uint4 u; f16x2 h[4]; };
union HU { f16 h; u16 u; };

#if defined(__has_builtin)
#if __has_builtin(__builtin_amdgcn_fdot2)
#define FDOT2(a,b,c) __builtin_amdgcn_fdot2(a, b, c, false)
#endif
#endif
#ifndef FDOT2
__device__ __forceinline__ float fdot2_sw(f16x2 a, f16x2 b, float c) {
  return c + (float)a[0]*(float)b[0] + (float)a[1]*(float)b[1];
}
#define FDOT2(a,b,c) fdot2_sw(a,b,c)
#endif

__device__ __forceinline__ unsigned f2ord(float f) {
  unsigned u = __float_as_uint(f);
  return (u & 0x80000000u) ? ~u : (u | 0x80000000u);
}
__device__ __forceinline__ float ord2f(unsigned o) {
  unsigned u = (o & 0x80000000u) ? (o ^ 0x80000000u) : ~o;
  return __uint_as_float(u);
}
__device__ __forceinline__ u16 f2bf(float f) {
  unsigned u = __float_as_uint(f);
  u += 0x7FFF + ((u >> 16) & 1);     // RTNE
  return (u16)(u >> 16);
}
__device__ __forceinline__ float bf2f(u16 h) {
  return __uint_as_float((unsigned)h << 16);
}

// ---------------------------------------------------------------------------
// Radix-256 top-k (4 byte passes, per-wave histograms, wave-0 suffix scan).
// ---------------------------------------------------------------------------
__device__ __forceinline__ void tk_radix(
    const unsigned key[8], int tid, int (*hist)[256], int* sel,
    unsigned& V, int& MEQ)
{
  const int lane = tid & 63, wid = tid >> 6;
  unsigned prefix = 0;
  int k = KTOP;
#pragma unroll
  for (int p = 0; p < 4; ++p) {
    const int shift = 24 - 8 * p;
    hist[0][tid] = 0; hist[1][tid] = 0; hist[2][tid] = 0; hist[3][tid] = 0;
    __syncthreads();
#pragma unroll
    for (int j = 0; j < 8; ++j) {
      unsigned kj = key[j];
      bool ok = (p == 0) || ((kj >> (shift + 8)) == prefix);
      if (ok) atomicAdd(&hist[wid][(kj >> shift) & 255], 1);
    }
    __syncthreads();
    {
      int c = hist[0][tid] + hist[1][tid] + hist[2][tid] + hist[3][tid];
      hist[0][tid] = c;
    }
    __syncthreads();
    if (wid == 0) {
      int m0 = hist[0][lane * 4 + 0], m1 = hist[0][lane * 4 + 1];
      int m2 = hist[0][lane * 4 + 2], m3 = hist[0][lane * 4 + 3];
      int sl = m0 + m1 + m2 + m3;
      int suf = sl;
#pragma unroll
      for (int off = 1; off < 64; off <<= 1) {
        int y = __shfl_down(suf, off, 64);
        if (lane + off < 64) suf += y;
      }
      int above = suf - sl;
      if (above < k && k <= suf) {
        int bin, nk;
        if (k <= above + m3)                { bin = lane*4+3; nk = k - above; }
        else if (k <= above + m3 + m2)      { bin = lane*4+2; nk = k - above - m3; }
        else if (k <= above + m3 + m2 + m1) { bin = lane*4+1; nk = k - above - m3 - m2; }
        else                                { bin = lane*4+0; nk = k - above - m3 - m2 - m1; }
        sel[0] = bin; sel[1] = nk;
      }
    }
    __syncthreads();
    prefix = (prefix << 8) | (unsigned)sel[0];
    k = sel[1];
    __syncthreads();
  }
  V = prefix;
  MEQ = k;
}

__device__ __forceinline__ int tk_scan_excl(int v, int tid, int* wsum) {
  const int lane = tid & 63, wid = tid >> 6;
  int x = v;
#pragma unroll
  for (int off = 1; off < 64; off <<= 1) {
    int y = __shfl_up(x, off, 64);
    if (lane >= off) x += y;
  }
  if (lane == 63) wsum[wid] = x;
  __syncthreads();
  int base = 0;
  for (int w = 0; w < wid; ++w) base += wsum[w];
  return base + x - v;
}

__device__ __forceinline__ void tk_write(const unsigned key[8], unsigned V, int MEQ,
                                         int tid, u16* orow, int* wsum) {
  int ceq = 0;
#pragma unroll
  for (int j = 0; j < 8; ++j) ceq += (key[j] == V) ? 1 : 0;
  int run = tk_scan_excl(ceq, tid, wsum);
  unsigned bits = 0;
#pragma unroll
  for (int j = 0; j < 8; ++j) {
    bool e = (key[j] == V);
    bool s = (key[j] > V) || (e && (run < MEQ));
    if (e) run++;
    if (s) bits |= (1u << j);
  }
  int csel = __popc(bits);
  __syncthreads();
  int base = tk_scan_excl(csel, tid, wsum);
#pragma unroll
  for (int j = 0; j < 8; ++j)
    if ((bits >> j) & 1u) orow[base++] = (u16)(tid * 8 + j);
}

// ---------------------------------------------------------------------------
// pack_all: bf16 hi/lo split of x (blocks 0..1023) and the 4 weight matrices
// (blocks 1024..1151); block 0 also zeroes the per-batch flag counters.
// ---------------------------------------------------------------------------
__global__ __launch_bounds__(256) void pack_all(
    const float* __restrict__ x,
    const float* __restrict__ W0, const float* __restrict__ W1,
    const float* __restrict__ W2, const float* __restrict__ W3,
    u16* __restrict__ xh, u16* __restrict__ xl, u16* __restrict__ wpk,
    int* __restrict__ flagcnt)
{
  const int lin = blockIdx.x;
  if (lin == 0 && threadIdx.x < NB) flagcnt[threadIdx.x] = 0;
  const float* src; u16 *dh, *dl; int i;
  if (lin < 1024) {
    src = x;
    i = (lin * 256 + threadIdx.x) * 8;
    dh = xh; dl = xl;
  } else {
    int j = lin - 1024;             // 0..127
    int m = j >> 5, bx = j & 31;
    src = (m == 0) ? W0 : (m == 1) ? W1 : (m == 2) ? W2 : W3;
    i = (bx * 256 + threadIdx.x) * 8;
    dh = wpk + (size_t)m * 2 * 65536;
    dl = dh + 65536;
  }
  float4 a = *(const float4*)(src + i);
  float4 b = *(const float4*)(src + i + 4);
  float v[8] = {a.x,a.y,a.z,a.w,b.x,b.y,b.z,b.w};
  u16 h[8], l[8];
#pragma unroll
  for (int j = 0; j < 8; ++j) {
    h[j] = f2bf(v[j]);
    l[j] = f2bf(v[j] - bf2f(h[j]));
  }
  uint4 ph, pl;
  ph.x = h[0] | ((unsigned)h[1] << 16); ph.y = h[2] | ((unsigned)h[3] << 16);
  ph.z = h[4] | ((unsigned)h[5] << 16); ph.w = h[6] | ((unsigned)h[7] << 16);
  pl.x = l[0] | ((unsigned)l[1] << 16); pl.y = l[2] | ((unsigned)l[3] << 16);
  pl.z = l[4] | ((unsigned)l[5] << 16); pl.w = l[6] | ((unsigned)l[7] << 16);
  *(uint4*)(dh + i) = ph;
  *(uint4*)(dl + i) = pl;
}

// ---------------------------------------------------------------------------
// fused_gemms: scores (SYMMETRIC — upper-triangle blocks only, mirror written
// from registers; blocks 0..543) + QKV projections (blocks 544..927).
// Scores use 3-term hi/lo MFMA (lo*lo dropped): adds ~3e-6 score error,
// 100x below MBOUND=4e-4, and scores only feed margin-guarded top-k.
// ---------------------------------------------------------------------------
__global__ __launch_bounds__(256) void fused_gemms(
    const u16* __restrict__ xh, const u16* __restrict__ xl,
    const u16* __restrict__ wpk,
    const float* __restrict__ bq, const float* __restrict__ bk,
    const float* __restrict__ bv,
    u16* __restrict__ qo, u16* __restrict__ ko, u16* __restrict__ vo,
    float* __restrict__ attnC)
{
  __shared__ u16 Ah[128 * 40], Al[128 * 40], Bh[128 * 40], Bl[128 * 40];
  const int lin = blockIdx.x;
  const int tid = threadIdx.x;
  const int wv = tid >> 6, ln = tid & 63;
  const int quad = ln >> 4, r16 = ln & 15;
  const int wm = (wv & 1) * 64, wn = (wv >> 1) * 64;
  const int srow = tid >> 1, shalf = (tid & 1) * 16;

  f32x4v acc[4][4];
#pragma unroll
  for (int i = 0; i < 4; ++i)
#pragma unroll
    for (int j = 0; j < 4; ++j) acc[i][j] = (f32x4v){0.f, 0.f, 0.f, 0.f};

  if (lin < 544) {
    // ----- scores path (symmetric, bi <= bj) -----
    const int b = lin / 136;
    int p = lin - b * 136;
    int bi = 0;
    while (p >= 16 - bi) { p -= 16 - bi; ++bi; }
    const int bj = bi + p;
    const int m0 = bi * 128, n0 = bj * 128;
    const u16* xhB = xh + (size_t)b * SEQ * EMB;
    const u16* xlB = xl + (size_t)b * SEQ * EMB;
    float* Cb = attnC + (size_t)b * SEQ * SEQ;
    for (int k0 = 0; k0 < EMB; k0 += 32) {
      __syncthreads();
      {
        size_t ga = (size_t)(m0 + srow) * EMB + k0 + shalf;
        size_t gb = (size_t)(n0 + srow) * EMB + k0 + shalf;
        uint4 ah0 = *(const uint4*)(xhB + ga), ah1 = *(const uint4*)(xhB + ga + 8);
        uint4 al0 = *(const uint4*)(xlB + ga), al1 = *(const uint4*)(xlB + ga + 8);
        uint4 bh0 = *(const uint4*)(xhB + gb), bh1 = *(const uint4*)(xhB + gb + 8);
        uint4 bl0 = *(const uint4*)(xlB + gb), bl1 = *(const uint4*)(xlB + gb + 8);
        int o = srow * 40 + shalf;
        *(uint4*)&Ah[o] = ah0; *(uint4*)&Ah[o + 8] = ah1;
        *(uint4*)&Al[o] = al0; *(uint4*)&Al[o + 8] = al1;
        *(uint4*)&Bh[o] = bh0; *(uint4*)&Bh[o + 8] = bh1;
        *(uint4*)&Bl[o] = bl0; *(uint4*)&Bl[o + 8] = bl1;
      }
      __syncthreads();
      frag8 fbh[4], fbl[4];
#pragma unroll
      for (int nt = 0; nt < 4; ++nt) {
        int ob = (wn + nt * 16 + r16) * 40 + quad * 8;
        fbh[nt] = *(const frag8*)&Bh[ob];
        fbl[nt] = *(const frag8*)&Bl[ob];
      }
#pragma unroll
      for (int mt = 0; mt < 4; ++mt) {
        int oa = (wm + mt * 16 + r16) * 40 + quad * 8;
        frag8 fah = *(const frag8*)&Ah[oa];
        frag8 fal = *(const frag8*)&Al[oa];
#pragma unroll
        for (int nt = 0; nt < 4; ++nt) {
          acc[mt][nt] = __builtin_amdgcn_mfma_f32_16x16x32_bf16(fah, fbh[nt], acc[mt][nt], 0, 0, 0);
          acc[mt][nt] = __builtin_amdgcn_mfma_f32_16x16x32_bf16(fah, fbl[nt], acc[mt][nt], 0, 0, 0);
          acc[mt][nt] = __builtin_amdgcn_mfma_f32_16x16x32_bf16(fal, fbh[nt], acc[mt][nt], 0, 0, 0);
        }
      }
    }
    // normal write (upper block)
#pragma unroll
    for (int mt = 0; mt < 4; ++mt)
#pragma unroll
      for (int nt = 0; nt < 4; ++nt) {
        int cg = n0 + wn + nt * 16 + r16;
        int rb = m0 + wm + mt * 16 + quad * 4;
#pragma unroll
        for (int r = 0; r < 4; ++r)
          Cb[(size_t)(rb + r) * SEQ + cg] = acc[mt][nt][r] * 0.0625f;
      }
    // mirror write (lower block): element (rb+r, cg) -> (cg, rb+r).
    // reg index r spans 4 consecutive COLUMNS of the mirror -> float4/lane.
    if (bi != bj) {
#pragma unroll
      for (int mt = 0; mt < 4; ++mt)
#pragma unroll
        for (int nt = 0; nt < 4; ++nt) {
          int cg = n0 + wn + nt * 16 + r16;
          int rb = m0 + wm + mt * 16 + quad * 4;
          float4 o;
          o.x = acc[mt][nt][0] * 0.0625f;
          o.y = acc[mt][nt][1] * 0.0625f;
          o.z = acc[mt][nt][2] * 0.0625f;
          o.w = acc[mt][nt][3] * 0.0625f;
          *(float4*)&Cb[(size_t)cg * SEQ + rb] = o;
        }
    }
  } else {
    // ----- qkv path -----
    const int j = lin - 544;
    const int m0 = (j & 63) * 128, n0 = ((j >> 6) & 1) * 128;
    const int z = j >> 7;
    const u16* Wh = wpk + (size_t)z * 2 * 65536;
    const u16* Wl = Wh + 65536;
    const float* bias = (z == 0) ? bq : (z == 1) ? bk : bv;
    u16* out = (z == 0) ? qo : (z == 1) ? ko : vo;
    for (int k0 = 0; k0 < EMB; k0 += 32) {
      __syncthreads();
      {
        size_t ga = (size_t)(m0 + srow) * EMB + k0 + shalf;
        size_t gb = (size_t)(n0 + srow) * EMB + k0 + shalf;
        uint4 ah0 = *(const uint4*)(xh + ga), ah1 = *(const uint4*)(xh + ga + 8);
        uint4 al0 = *(const uint4*)(xl + ga), al1 = *(const uint4*)(xl + ga + 8);
        uint4 bh0 = *(const uint4*)(Wh + gb), bh1 = *(const uint4*)(Wh + gb + 8);
        uint4 bl0 = *(const uint4*)(Wl + gb), bl1 = *(const uint4*)(Wl + gb + 8);
        int o = srow * 40 + shalf;
        *(uint4*)&Ah[o] = ah0; *(uint4*)&Ah[o + 8] = ah1;
        *(uint4*)&Al[o] = al0; *(uint4*)&Al[o + 8] = al1;
        *(uint4*)&Bh[o] = bh0; *(uint4*)&Bh[o + 8] = bh1;
        *(uint4*)&Bl[o] = bl0; *(uint4*)&Bl[o + 8] = bl1;
      }
      __syncthreads();
      frag8 fbh[4], fbl[4];
#pragma unroll
      for (int nt = 0; nt < 4; ++nt) {
        int ob = (wn + nt * 16 + r16) * 40 + quad * 8;
        fbh[nt] = *(const frag8*)&Bh[ob];
        fbl[nt] = *(const frag8*)&Bl[ob];
      }
#pragma unroll
      for (int mt = 0; mt < 4; ++mt) {
        int oa = (wm + mt * 16 + r16) * 40 + quad * 8;
        frag8 fah = *(const frag8*)&Ah[oa];
        frag8 fal = *(const frag8*)&Al[oa];
#pragma unroll
        for (int nt = 0; nt < 4; ++nt) {
          acc[mt][nt] = __builtin_amdgcn_mfma_f32_16x16x32_bf16(fah, fbh[nt], acc[mt][nt], 0, 0, 0);
          acc[mt][nt] = __builtin_amdgcn_mfma_f32_16x16x32_bf16(fah, fbl[nt], acc[mt][nt], 0, 0, 0);
          acc[mt][nt] = __builtin_amdgcn_mfma_f32_16x16x32_bf16(fal, fbh[nt], acc[mt][nt], 0, 0, 0);
        }
      }
    }
#pragma unroll
    for (int nt = 0; nt < 4; ++nt) {
      int cg = n0 + wn + nt * 16 + r16;
      float bvv = bias[cg];
#pragma unroll
      for (int mt = 0; mt < 4; ++mt) {
        int rb = m0 + wm + mt * 16 + quad * 4;
#pragma unroll
        for (int r = 0; r < 4; ++r) {
          HU hu; hu.h = (f16)(acc[mt][nt][r] + bvv);
          out[(size_t)(rb + r) * EMB + cg] = hu.u;
        }
      }
    }
  }
}

// ---------------------------------------------------------------------------
// Out projection: stages fp32 ctx, splits hi/lo in-kernel (3-term MFMA).
// ---------------------------------------------------------------------------
__global__ __launch_bounds__(256) void out_mfma(
    const float* __restrict__ ctx, const u16* __restrict__ wpk,
    const float* __restrict__ bias, float* __restrict__ out)
{
  const u16* Wh = wpk + (size_t)3 * 2 * 65536;
  const u16* Wl = Wh + 65536;
  __shared__ u16 Ah[128 * 40], Al[128 * 40], Bh[128 * 40], Bl[128 * 40];
  const int tid = threadIdx.x;
  const int m0 = blockIdx.x * 128, n0 = blockIdx.y * 128;
  const int wv = tid >> 6, ln = tid & 63;
  const int quad = ln >> 4, r16 = ln & 15;
  const int wm = (wv & 1) * 64, wn = (wv >> 1) * 64;
  const int srow = tid >> 1, shalf = (tid & 1) * 16;

  f32x4v acc[4][4];
#pragma unroll
  for (int i = 0; i < 4; ++i)
#pragma unroll
    for (int j = 0; j < 4; ++j) acc[i][j] = (f32x4v){0.f, 0.f, 0.f, 0.f};

  for (int k0 = 0; k0 < EMB; k0 += 32) {
    __syncthreads();
    {
      size_t ga = (size_t)(m0 + srow) * EMB + k0 + shalf;
      float4 c0 = *(const float4*)(ctx + ga);
      float4 c1 = *(const float4*)(ctx + ga + 4);
      float4 c2 = *(const float4*)(ctx + ga + 8);
      float4 c3 = *(const float4*)(ctx + ga + 12);
      float v[16] = {c0.x,c0.y,c0.z,c0.w, c1.x,c1.y,c1.z,c1.w,
                     c2.x,c2.y,c2.z,c2.w, c3.x,c3.y,c3.z,c3.w};
      u16 hh[16], ll[16];
#pragma unroll
      for (int jj = 0; jj < 16; ++jj) {
        hh[jj] = f2bf(v[jj]);
        ll[jj] = f2bf(v[jj] - bf2f(hh[jj]));
      }
      int o = srow * 40 + shalf;
#pragma unroll
      for (int g = 0; g < 2; ++g) {
        uint4 ph, pl;
        ph.x = hh[g*8+0] | ((unsigned)hh[g*8+1] << 16);
        ph.y = hh[g*8+2] | ((unsigned)hh[g*8+3] << 16);
        ph.z = hh[g*8+4] | ((unsigned)hh[g*8+5] << 16);
        ph.w = hh[g*8+6] | ((unsigned)hh[g*8+7] << 16);
        pl.x = ll[g*8+0] | ((unsigned)ll[g*8+1] << 16);
        pl.y = ll[g*8+2] | ((unsigned)ll[g*8+3] << 16);
        pl.z = ll[g*8+4] | ((unsigned)ll[g*8+5] << 16);
        pl.w = ll[g*8+6] | ((unsigned)ll[g*8+7] << 16);
        *(uint4*)&Ah[o + g*8] = ph;
        *(uint4*)&Al[o + g*8] = pl;
      }
      size_t gb = (size_t)(n0 + srow) * EMB + k0 + shalf;
      uint4 bh0 = *(const uint4*)(Wh + gb), bh1 = *(const uint4*)(Wh + gb + 8);
      uint4 bl0 = *(const uint4*)(Wl + gb), bl1 = *(const uint4*)(Wl + gb + 8);
      *(uint4*)&Bh[o] = bh0; *(uint4*)&Bh[o + 8] = bh1;
      *(uint4*)&Bl[o] = bl0; *(uint4*)&Bl[o + 8] = bl1;
    }
    __syncthreads();
    frag8 fbh[4], fbl[4];
#pragma unroll
    for (int nt = 0; nt < 4; ++nt) {
      int ob = (wn + nt * 16 + r16) * 40 + quad * 8;
      fbh[nt] = *(const frag8*)&Bh[ob];
      fbl[nt] = *(const frag8*)&Bl[ob];
    }
#pragma unroll
    for (int mt = 0; mt < 4; ++mt) {
      int oa = (wm + mt * 16 + r16) * 40 + quad * 8;
      frag8 fah = *(const frag8*)&Ah[oa];
      frag8 fal = *(const frag8*)&Al[oa];
#pragma unroll
      for (int nt = 0; nt < 4; ++nt) {
        acc[mt][nt] = __builtin_amdgcn_mfma_f32_16x16x32_bf16(fah, fbh[nt], acc[mt][nt], 0, 0, 0);
        acc[mt][nt] = __builtin_amdgcn_mfma_f32_16x16x32_bf16(fah, fbl[nt], acc[mt][nt], 0, 0, 0);
        acc[mt][nt] = __builtin_amdgcn_mfma_f32_16x16x32_bf16(fal, fbh[nt], acc[mt][nt], 0, 0, 0);
      }
    }
  }
#pragma unroll
  for (int nt = 0; nt < 4; ++nt) {
    int cg = n0 + wn + nt * 16 + r16;
    float bvv = bias[cg];
#pragma unroll
    for (int mt = 0; mt < 4; ++mt) {
      int rb = m0 + wm + mt * 16 + quad * 4;
#pragma unroll
      for (int r = 0; r < 4; ++r)
        out[(size_t)(rb + r) * EMB + cg] = acc[mt][nt][r] + bvv;
    }
  }
}

// ---------------------------------------------------------------------------
// Top-k per row (radix-256), with margin flagging into per-batch lists.
// ---------------------------------------------------------------------------
__global__ __launch_bounds__(256) void topk_idx(
    const float* __restrict__ scores, u16* __restrict__ idxl,
    int* __restrict__ flagcnt, int* __restrict__ flaglist)
{
  __shared__ int hist[4][256];
  __shared__ int sel[2];
  __shared__ int wsum[4];
  __shared__ unsigned wmax[4];
  const int r = blockIdx.x;
  const int tid = threadIdx.x;
  const int lane = tid & 63, wid = tid >> 6;
  const float* row = scores + (size_t)r * SEQ;
  unsigned key[8];
  {
    float4 f0 = *(const float4*)(row + tid * 8);
    float4 f1 = *(const float4*)(row + tid * 8 + 4);
    key[0]=f2ord(f0.x); key[1]=f2ord(f0.y); key[2]=f2ord(f0.z); key[3]=f2ord(f0.w);
    key[4]=f2ord(f1.x); key[5]=f2ord(f1.y); key[6]=f2ord(f1.z); key[7]=f2ord(f1.w);
  }
  unsigned V; int MEQ;
  tk_radix(key, tid, hist, sel, V, MEQ);

  {
    int ceq = 0; unsigned mk = 0;
#pragma unroll
    for (int j = 0; j < 8; ++j) {
      ceq += (key[j] == V) ? 1 : 0;
      if (key[j] < V && key[j] > mk) mk = key[j];
    }
#pragma unroll
    for (int off = 32; off > 0; off >>= 1) {
      ceq += __shfl_down(ceq, off, 64);
      unsigned o = (unsigned)__shfl_down((int)mk, off, 64);
      if (o > mk) mk = o;
    }
    if (lane == 0) { wsum[wid] = ceq; wmax[wid] = mk; }
    __syncthreads();
    if (tid == 0) {
      int EQ = wsum[0] + wsum[1] + wsum[2] + wsum[3];
      unsigned m2 = wmax[0];
      for (int w = 1; w < 4; ++w) if (wmax[w] > m2) m2 = wmax[w];
      bool flag = (EQ > MEQ) || !(ord2f(V) - ord2f(m2) >= MBOUND);
      if (flag) {
        int bb = r >> 11;
        int p = atomicAdd(&flagcnt[bb], 1);
        flaglist[bb * SEQ + p] = r & (SEQ - 1);
      }
    }
    __syncthreads();
  }

  tk_write(key, V, MEQ, tid, idxl + (size_t)r * IDXP, wsum);
}

// ---------------------------------------------------------------------------
// Fixup A: exact fp32 scores for flagged rows (gathered-A 64x64 GEMM).
// ---------------------------------------------------------------------------
__global__ __launch_bounds__(256) void fixup_gemm(
    const float* __restrict__ x, const int* __restrict__ flagcnt,
    const int* __restrict__ flaglist, float* __restrict__ attn)
{
  const int b = blockIdx.z;
  const int n = flagcnt[b];
  const int g0 = blockIdx.y * 64;
  if (g0 >= n) return;
  __shared__ float As[16][68];
  __shared__ float Bs[16][68];
  __shared__ int rowsh[64];
  const int tid = threadIdx.x;
  const int n0 = blockIdx.x * 64;
  if (tid < 64) {
    int gi = g0 + tid;
    rowsh[tid] = (gi < n) ? flaglist[b * SEQ + gi] : -1;
  }
  __syncthreads();
  const float* xb = x + (size_t)b * SEQ * EMB;
  const int lm = tid >> 2;
  const int lk = (tid & 3) << 2;
  const int mt = tid >> 4;
  const int nt = tid & 15;
  const int arow = rowsh[lm];
  const int arowL = (arow < 0) ? 0 : arow;
  float acc[4][4] = {{0.f}};
  for (int k0 = 0; k0 < EMB; k0 += 16) {
    float4 av = *(const float4*)(xb + (size_t)arowL * EMB + k0 + lk);
    float4 bv = *(const float4*)(xb + (size_t)(n0 + lm) * EMB + k0 + lk);
    __syncthreads();
    As[lk+0][lm] = av.x; As[lk+1][lm] = av.y; As[lk+2][lm] = av.z; As[lk+3][lm] = av.w;
    Bs[lk+0][lm] = bv.x; Bs[lk+1][lm] = bv.y; Bs[lk+2][lm] = bv.z; Bs[lk+3][lm] = bv.w;
    __syncthreads();
#pragma unroll
    for (int kk = 0; kk < 16; ++kk) {
      float4 a4 = *(const float4*)&As[kk][mt << 2];
      float4 b4 = *(const float4*)&Bs[kk][nt << 2];
      acc[0][0] += a4.x*b4.x; acc[0][1] += a4.x*b4.y; acc[0][2] += a4.x*b4.z; acc[0][3] += a4.x*b4.w;
      acc[1][0] += a4.y*b4.x; acc[1][1] += a4.y*b4.y; acc[1][2] += a4.y*b4.z; acc[1][3] += a4.y*b4.w;
      acc[2][0] += a4.z*b4.x; acc[2][1] += a4.z*b4.y; acc[2][2] += a4.z*b4.z; acc[2][3] += a4.z*b4.w;
      acc[3][0] += a4.w*b4.x; acc[3][1] += a4.w*b4.y; acc[3][2] += a4.w*b4.z; acc[3][3] += a4.w*b4.w;
    }
  }
  float* attnB = attn + (size_t)b * SEQ * SEQ;
#pragma unroll
  for (int r = 0; r < 4; ++r) {
    int rr = rowsh[(mt << 2) + r];
    if (rr >= 0) {
      float4 o;
      o.x = acc[r][0] * 0.0625f; o.y = acc[r][1] * 0.0625f;
      o.z = acc[r][2] * 0.0625f; o.w = acc[r][3] * 0.0625f;
      *(float4*)(attnB + (size_t)rr * SEQ + n0 + (nt << 2)) = o;
    }
  }
}

// ---------------------------------------------------------------------------
// Fixup B: redo top-k (radix) on the now-exact flagged rows.
// ---------------------------------------------------------------------------
__global__ __launch_bounds__(256) void topk_fixup(
    const float* __restrict__ attn, const int* __restrict__ flagcnt,
    const int* __restrict__ flaglist, u16* __restrict__ idxl)
{
  const int b = blockIdx.y;
  if ((int)blockIdx.x >= flagcnt[b]) return;
  const int r = b * SEQ + flaglist[b * SEQ + blockIdx.x];
  __shared__ int hist[4][256];
  __shared__ int sel[2];
  __shared__ int wsum[4];
  const int tid = threadIdx.x;
  const float* row = attn + (size_t)r * SEQ;
  unsigned key[8];
  {
    float4 f0 = *(const float4*)(row + tid * 8);
    float4 f1 = *(const float4*)(row + tid * 8 + 4);
    key[0]=f2ord(f0.x); key[1]=f2ord(f0.y); key[2]=f2ord(f0.z); key[3]=f2ord(f0.w);
    key[4]=f2ord(f1.x); key[5]=f2ord(f1.y); key[6]=f2ord(f1.z); key[7]=f2ord(f1.w);
  }
  unsigned V; int MEQ;
  tk_radix(key, tid, hist, sel, V, MEQ);
  tk_write(key, V, MEQ, tid, idxl + (size_t)r * IDXP, wsum);
}

// ---------------------------------------------------------------------------
// Sparse attention v7: SINGLE fused gather pass. After the 4-lane shfl_xor
// reduce every lane of a head-group holds the full dot s, and its V-dims
// (d0 = sl*8) belong to that same head -> PV accumulates UNNORMALIZED
// (a8 += exp(s)*v) in the same iteration, K and V gathers issued
// back-to-back from the same offset. 1/den applied once at the end.
// Removes the second 26-iter loop (psh re-reads, addr math, one barrier).
// ---------------------------------------------------------------------------
__global__ __launch_bounds__(256) void sparse_attn(
    const u16* __restrict__ qf, const u16* __restrict__ kf,
    const u16* __restrict__ vf, const u16* __restrict__ idxl,
    float* __restrict__ attn, float* __restrict__ ctxb)
{
  const int lin = blockIdx.x;
  const int b = lin & 3;                                  // XCD-stable batch
  const int q = (lin >> 3) + (((lin >> 2) & 1) << 10);
  const int tid = threadIdx.x;
  const int wv = tid >> 6, ln = tid & 63;
  const int half = ln >> 5, sl = ln & 31;
  const int h = sl >> 2, d0 = sl * 8;
  const int lb = sl * 16;
  __shared__ int   ish[IDXP];
  __shared__ int   koff[IDXP];
  __shared__ float psh[IDXP * 9 + 4];   // [j][h], stride 9 (raw exp, unnormalized)
  __shared__ float idsh[NH];
  __shared__ float rcsh[2112];          // union: rsh[2048] | csh[8][264]
#define CSH(i, j) rcsh[(i) * 264 + (j)]

  const int row = b * SEQ + q;
  if (tid < KTOP) {
    int idx = (int)idxl[(size_t)row * IDXP + tid];
    ish[tid] = idx;
    koff[tid] = idx << 9;
  } else if (tid < IDXP) {
    ish[tid] = 0; koff[tid] = 0;
  }

  float4 z4 = make_float4(0.f, 0.f, 0.f, 0.f);
  *(float4*)&rcsh[tid * 4]        = z4;
  *(float4*)&rcsh[1024 + tid * 4] = z4;

  U4 qv;
  qv.u = *(const uint4*)((const char*)(qf + (size_t)row * EMB) + lb);

  __syncthreads();

  const float scale = 0.17677669529663687f;  // 1/sqrt(32)
  const char* kbC = (const char*)(kf + (size_t)(b * SEQ) * EMB);
  const char* vbC = (const char*)(vf + (size_t)(b * SEQ) * EMB);
  const int jb = wv * KPW;
  float a8[8] = {0.f,0.f,0.f,0.f,0.f,0.f,0.f,0.f};
#pragma unroll 4
  for (int t = 0; t < KPW; t += 2) {
    const int j = jb + t + half;
    const int off = koff[j];
    U4 kv, vv;
    kv.u = *(const uint4*)(kbC + (off + lb));
    vv.u = *(const uint4*)(vbC + (off + lb));
    float s = FDOT2(qv.h[0], kv.h[0],
              FDOT2(qv.h[1], kv.h[1],
              FDOT2(qv.h[2], kv.h[2],
              FDOT2(qv.h[3], kv.h[3], 0.f))));
    s += __shfl_xor(s, 1, 64);
    s += __shfl_xor(s, 2, 64);
    float p = (j < KTOP) ? __expf(s * scale) : 0.f;
    if ((sl & 3) == 0 && j < KTOP) psh[j * 9 + h] = p;
    a8[0] += p * (float)vv.h[0][0]; a8[1] += p * (float)vv.h[0][1];
    a8[2] += p * (float)vv.h[1][0]; a8[3] += p * (float)vv.h[1][1];
    a8[4] += p * (float)vv.h[2][0]; a8[5] += p * (float)vv.h[2][1];
    a8[6] += p * (float)vv.h[3][0]; a8[7] += p * (float)vv.h[3][1];
  }
  __syncthreads();

  // per-head denominators
  {
    int h2 = tid >> 5, l = tid & 31;
    float sden = 0.f;
    for (int j = l; j < KTOP; j += 32) sden += psh[j * 9 + h2];
#pragma unroll
    for (int off = 16; off > 0; off >>= 1) sden += __shfl_down(sden, off, 32);
    if (l == 0) idsh[h2] = 1.0f / sden;
  }
  __syncthreads();

  // head-averaged normalized probs -> scatter into the dense row
  if (tid < KTOP) {
    float ps = 0.f;
#pragma unroll
    for (int hh = 0; hh < 8; ++hh) ps += psh[tid * 9 + hh] * idsh[hh];
    rcsh[ish[tid]] = ps * 0.125f;
  }
  __syncthreads();

  // stream dense row out (full-line, conflict-free)
  {
    float* arow = attn + (size_t)row * SEQ;
    *(float4*)(arow + tid * 4)        = *(const float4*)&rcsh[tid * 4];
    *(float4*)(arow + 1024 + tid * 4) = *(const float4*)&rcsh[1024 + tid * 4];
  }
  __syncthreads();   // rsh dead; csh may now overwrite the region

  // normalize context partials (late 1/den) and reduce across wave-halves
  {
    const float sc = idsh[h];
    const int pi = wv * 2 + half;
    *(float4*)&CSH(pi, d0)     = make_float4(a8[0]*sc, a8[1]*sc, a8[2]*sc, a8[3]*sc);
    *(float4*)&CSH(pi, d0 + 4) = make_float4(a8[4]*sc, a8[5]*sc, a8[6]*sc, a8[7]*sc);
  }
  __syncthreads();
  if (tid < 64) {
    float4 o = z4;
#pragma unroll
    for (int g = 0; g < 8; ++g) {
      float4 v = *(const float4*)&CSH(g, tid * 4);
      o.x += v.x; o.y += v.y; o.z += v.z; o.w += v.w;
    }
    *(float4*)(ctxb + (size_t)row * EMB + tid * 4) = o;
  }
#undef CSH
}

// ---------------------------------------------------------------------------
extern "C" void kernel_launch(void* const* d_in, const int* in_sizes, int n_in,
                              void* d_out, int out_size, void* d_ws, size_t ws_size,
                              hipStream_t stream)
{
  const float* x  = (const float*)d_in[0];
  const float* Wq = (const float*)d_in[1];
  const float* bq = (const float*)d_in[2];
  const float* Wk = (const float*)d_in[3];
  const float* bk = (const float*)d_in[4];
  const float* Wv = (const float*)d_in[5];
  const float* bv = (const float*)d_in[6];
  const float* Wo = (const float*)d_in[7];
  const float* bo = (const float*)d_in[8];

  float* out  = (float*)d_out;
  float* attn = out + (size_t)NB * SEQ * EMB;   // [B,S,S] region of d_out

  const size_t NSE = (size_t)NB * SEQ * EMB;    // 2097152
  u16* xh  = (u16*)d_ws;            // bf16 hi of x
  u16* xl  = xh + NSE;              // bf16 lo
  u16* qf  = xl + NSE;              // f16 Q
  u16* kf  = qf + NSE;              // f16 K
  u16* vf  = kf + NSE;              // f16 V
  u16* wpk = vf + NSE;              // 4 x (hi,lo) 256x256 bf16
  float* ctxb = (float*)(wpk + 4 * 2 * 65536);
  u16* idxl = (u16*)(ctxb + NSE);
  int* flagcnt  = (int*)(idxl + (size_t)NB * SEQ * IDXP);
  int* flaglist = flagcnt + NB;

  const dim3 blk(256);

  // hi/lo splits of x + weights (one launch); flag counters reset
  pack_all<<<dim3(1152), blk, 0, stream>>>(x, Wq, Wk, Wv, Wo, xh, xl, wpk, flagcnt);

  // symmetric scores (544 upper-triangle blocks) + QKV (384) in one launch
  fused_gemms<<<dim3(928), blk, 0, stream>>>(xh, xl, wpk, bq, bk, bv,
                                             qf, kf, vf, attn);

  // radix top-k with margin flagging; exact fp32 fixup of low-margin rows
  topk_idx<<<dim3(NB * SEQ), blk, 0, stream>>>(attn, idxl, flagcnt, flaglist);
  fixup_gemm<<<dim3(32, 32, NB), blk, 0, stream>>>(x, flagcnt, flaglist, attn);
  topk_fixup<<<dim3(SEQ, NB), blk, 0, stream>>>(attn, flagcnt, flaglist, idxl);

  // fused single-pass sparse attention (K+V gathered together, late 1/den)
  sparse_attn<<<dim3(SEQ * NB), blk, 0, stream>>>(qf, kf, vf, idxl, attn, ctxb);

  // out = ctx @ Wo^T + bo (in-kernel hi/lo split of ctx)
  out_mfma<<<dim3(64, 2), blk, 0, stream>>>(ctxb, wpk, bo, out);
}

// Round 4
// 324.525 us; speedup vs baseline: 1.0792x; 1.0792x over previous
//
#include <hip/hip_runtime.h>

#define SEQ  2048
#define EMB  256
#define NH   8
#define HD   32
#define NB   4
#define KTOP 204
#define IDXP 208
#define KPW  52       // keys per wave (4*52 = 208, padded)
#define MBOUND 4e-4f  // top-k margin for fp32 re-verify

typedef unsigned long long ull;
typedef unsigned short u16;

using frag8  = __attribute__((ext_vector_type(8))) short;  // 8 bf16
using f32x4v = __attribute__((ext_vector_type(4))) float;
typedef _Float16 f16;
typedef _Float16 f16x2 __attribute__((ext_vector_type(2)));

union U4 { uint4 u; f16x2 h[4]; };
union HU { f16 h; u16 u; };

#if defined(__has_builtin)
#if __has_builtin(__builtin_amdgcn_fdot2)
#define FDOT2(a,b,c) __builtin_amdgcn_fdot2(a, b, c, false)
#endif
#endif
#ifndef FDOT2
__device__ __forceinline__ float fdot2_sw(f16x2 a, f16x2 b, float c) {
  return c + (float)a[0]*(float)b[0] + (float)a[1]*(float)b[1];
}
#define FDOT2(a,b,c) fdot2_sw(a,b,c)
#endif

__device__ __forceinline__ unsigned f2ord(float f) {
  unsigned u = __float_as_uint(f);
  return (u & 0x80000000u) ? ~u : (u | 0x80000000u);
}
__device__ __forceinline__ float ord2f(unsigned o) {
  unsigned u = (o & 0x80000000u) ? (o ^ 0x80000000u) : ~o;
  return __uint_as_float(u);
}
__device__ __forceinline__ u16 f2bf(float f) {
  unsigned u = __float_as_uint(f);
  u += 0x7FFF + ((u >> 16) & 1);     // RTNE
  return (u16)(u >> 16);
}
__device__ __forceinline__ float bf2f(u16 h) {
  return __uint_as_float((unsigned)h << 16);
}

// ---------------------------------------------------------------------------
// Radix-256 top-k (4 byte passes, per-wave histograms, wave-0 suffix scan).
// ---------------------------------------------------------------------------
__device__ __forceinline__ void tk_radix(
    const unsigned key[8], int tid, int (*hist)[256], int* sel,
    unsigned& V, int& MEQ)
{
  const int lane = tid & 63, wid = tid >> 6;
  unsigned prefix = 0;
  int k = KTOP;
#pragma unroll
  for (int p = 0; p < 4; ++p) {
    const int shift = 24 - 8 * p;
    hist[0][tid] = 0; hist[1][tid] = 0; hist[2][tid] = 0; hist[3][tid] = 0;
    __syncthreads();
#pragma unroll
    for (int j = 0; j < 8; ++j) {
      unsigned kj = key[j];
      bool ok = (p == 0) || ((kj >> (shift + 8)) == prefix);
      if (ok) atomicAdd(&hist[wid][(kj >> shift) & 255], 1);
    }
    __syncthreads();
    {
      int c = hist[0][tid] + hist[1][tid] + hist[2][tid] + hist[3][tid];
      hist[0][tid] = c;
    }
    __syncthreads();
    if (wid == 0) {
      int m0 = hist[0][lane * 4 + 0], m1 = hist[0][lane * 4 + 1];
      int m2 = hist[0][lane * 4 + 2], m3 = hist[0][lane * 4 + 3];
      int sl = m0 + m1 + m2 + m3;
      int suf = sl;
#pragma unroll
      for (int off = 1; off < 64; off <<= 1) {
        int y = __shfl_down(suf, off, 64);
        if (lane + off < 64) suf += y;
      }
      int above = suf - sl;
      if (above < k && k <= suf) {
        int bin, nk;
        if (k <= above + m3)                { bin = lane*4+3; nk = k - above; }
        else if (k <= above + m3 + m2)      { bin = lane*4+2; nk = k - above - m3; }
        else if (k <= above + m3 + m2 + m1) { bin = lane*4+1; nk = k - above - m3 - m2; }
        else                                { bin = lane*4+0; nk = k - above - m3 - m2 - m1; }
        sel[0] = bin; sel[1] = nk;
      }
    }
    __syncthreads();
    prefix = (prefix << 8) | (unsigned)sel[0];
    k = sel[1];
    __syncthreads();
  }
  V = prefix;
  MEQ = k;
}

__device__ __forceinline__ int tk_scan_excl(int v, int tid, int* wsum) {
  const int lane = tid & 63, wid = tid >> 6;
  int x = v;
#pragma unroll
  for (int off = 1; off < 64; off <<= 1) {
    int y = __shfl_up(x, off, 64);
    if (lane >= off) x += y;
  }
  if (lane == 63) wsum[wid] = x;
  __syncthreads();
  int base = 0;
  for (int w = 0; w < wid; ++w) base += wsum[w];
  return base + x - v;
}

__device__ __forceinline__ void tk_write(const unsigned key[8], unsigned V, int MEQ,
                                         int tid, u16* orow, int* wsum) {
  int ceq = 0;
#pragma unroll
  for (int j = 0; j < 8; ++j) ceq += (key[j] == V) ? 1 : 0;
  int run = tk_scan_excl(ceq, tid, wsum);
  unsigned bits = 0;
#pragma unroll
  for (int j = 0; j < 8; ++j) {
    bool e = (key[j] == V);
    bool s = (key[j] > V) || (e && (run < MEQ));
    if (e) run++;
    if (s) bits |= (1u << j);
  }
  int csel = __popc(bits);
  __syncthreads();
  int base = tk_scan_excl(csel, tid, wsum);
#pragma unroll
  for (int j = 0; j < 8; ++j)
    if ((bits >> j) & 1u) orow[base++] = (u16)(tid * 8 + j);
}

// ---------------------------------------------------------------------------
// pack_all: bf16 hi/lo split of x (blocks 0..1023) and the 4 weight matrices
// (blocks 1024..1151); block 0 also zeroes the per-batch flag counters.
// ---------------------------------------------------------------------------
__global__ __launch_bounds__(256) void pack_all(
    const float* __restrict__ x,
    const float* __restrict__ W0, const float* __restrict__ W1,
    const float* __restrict__ W2, const float* __restrict__ W3,
    u16* __restrict__ xh, u16* __restrict__ xl, u16* __restrict__ wpk,
    int* __restrict__ flagcnt)
{
  const int lin = blockIdx.x;
  if (lin == 0 && threadIdx.x < NB) flagcnt[threadIdx.x] = 0;
  const float* src; u16 *dh, *dl; int i;
  if (lin < 1024) {
    src = x;
    i = (lin * 256 + threadIdx.x) * 8;
    dh = xh; dl = xl;
  } else {
    int j = lin - 1024;             // 0..127
    int m = j >> 5, bx = j & 31;
    src = (m == 0) ? W0 : (m == 1) ? W1 : (m == 2) ? W2 : W3;
    i = (bx * 256 + threadIdx.x) * 8;
    dh = wpk + (size_t)m * 2 * 65536;
    dl = dh + 65536;
  }
  float4 a = *(const float4*)(src + i);
  float4 b = *(const float4*)(src + i + 4);
  float v[8] = {a.x,a.y,a.z,a.w,b.x,b.y,b.z,b.w};
  u16 h[8], l[8];
#pragma unroll
  for (int j = 0; j < 8; ++j) {
    h[j] = f2bf(v[j]);
    l[j] = f2bf(v[j] - bf2f(h[j]));
  }
  uint4 ph, pl;
  ph.x = h[0] | ((unsigned)h[1] << 16); ph.y = h[2] | ((unsigned)h[3] << 16);
  ph.z = h[4] | ((unsigned)h[5] << 16); ph.w = h[6] | ((unsigned)h[7] << 16);
  pl.x = l[0] | ((unsigned)l[1] << 16); pl.y = l[2] | ((unsigned)l[3] << 16);
  pl.z = l[4] | ((unsigned)l[5] << 16); pl.w = l[6] | ((unsigned)l[7] << 16);
  *(uint4*)(dh + i) = ph;
  *(uint4*)(dl + i) = pl;
}

// ---------------------------------------------------------------------------
// fused_gemms: scores (SYMMETRIC — upper-triangle blocks only, mirror written
// from registers; blocks 0..543) + QKV projections (blocks 544..927).
// Scores use 3-term hi/lo MFMA (lo*lo dropped): adds ~3e-6 score error,
// 100x below MBOUND=4e-4, and scores only feed margin-guarded top-k.
// ---------------------------------------------------------------------------
__global__ __launch_bounds__(256) void fused_gemms(
    const u16* __restrict__ xh, const u16* __restrict__ xl,
    const u16* __restrict__ wpk,
    const float* __restrict__ bq, const float* __restrict__ bk,
    const float* __restrict__ bv,
    u16* __restrict__ qo, u16* __restrict__ ko, u16* __restrict__ vo,
    float* __restrict__ attnC)
{
  __shared__ u16 Ah[128 * 40], Al[128 * 40], Bh[128 * 40], Bl[128 * 40];
  const int lin = blockIdx.x;
  const int tid = threadIdx.x;
  const int wv = tid >> 6, ln = tid & 63;
  const int quad = ln >> 4, r16 = ln & 15;
  const int wm = (wv & 1) * 64, wn = (wv >> 1) * 64;
  const int srow = tid >> 1, shalf = (tid & 1) * 16;

  f32x4v acc[4][4];
#pragma unroll
  for (int i = 0; i < 4; ++i)
#pragma unroll
    for (int j = 0; j < 4; ++j) acc[i][j] = (f32x4v){0.f, 0.f, 0.f, 0.f};

  if (lin < 544) {
    // ----- scores path (symmetric, bi <= bj) -----
    const int b = lin / 136;
    int p = lin - b * 136;
    int bi = 0;
    while (p >= 16 - bi) { p -= 16 - bi; ++bi; }
    const int bj = bi + p;
    const int m0 = bi * 128, n0 = bj * 128;
    const u16* xhB = xh + (size_t)b * SEQ * EMB;
    const u16* xlB = xl + (size_t)b * SEQ * EMB;
    float* Cb = attnC + (size_t)b * SEQ * SEQ;
    for (int k0 = 0; k0 < EMB; k0 += 32) {
      __syncthreads();
      {
        size_t ga = (size_t)(m0 + srow) * EMB + k0 + shalf;
        size_t gb = (size_t)(n0 + srow) * EMB + k0 + shalf;
        uint4 ah0 = *(const uint4*)(xhB + ga), ah1 = *(const uint4*)(xhB + ga + 8);
        uint4 al0 = *(const uint4*)(xlB + ga), al1 = *(const uint4*)(xlB + ga + 8);
        uint4 bh0 = *(const uint4*)(xhB + gb), bh1 = *(const uint4*)(xhB + gb + 8);
        uint4 bl0 = *(const uint4*)(xlB + gb), bl1 = *(const uint4*)(xlB + gb + 8);
        int o = srow * 40 + shalf;
        *(uint4*)&Ah[o] = ah0; *(uint4*)&Ah[o + 8] = ah1;
        *(uint4*)&Al[o] = al0; *(uint4*)&Al[o + 8] = al1;
        *(uint4*)&Bh[o] = bh0; *(uint4*)&Bh[o + 8] = bh1;
        *(uint4*)&Bl[o] = bl0; *(uint4*)&Bl[o + 8] = bl1;
      }
      __syncthreads();
      frag8 fbh[4], fbl[4];
#pragma unroll
      for (int nt = 0; nt < 4; ++nt) {
        int ob = (wn + nt * 16 + r16) * 40 + quad * 8;
        fbh[nt] = *(const frag8*)&Bh[ob];
        fbl[nt] = *(const frag8*)&Bl[ob];
      }
#pragma unroll
      for (int mt = 0; mt < 4; ++mt) {
        int oa = (wm + mt * 16 + r16) * 40 + quad * 8;
        frag8 fah = *(const frag8*)&Ah[oa];
        frag8 fal = *(const frag8*)&Al[oa];
#pragma unroll
        for (int nt = 0; nt < 4; ++nt) {
          acc[mt][nt] = __builtin_amdgcn_mfma_f32_16x16x32_bf16(fah, fbh[nt], acc[mt][nt], 0, 0, 0);
          acc[mt][nt] = __builtin_amdgcn_mfma_f32_16x16x32_bf16(fah, fbl[nt], acc[mt][nt], 0, 0, 0);
          acc[mt][nt] = __builtin_amdgcn_mfma_f32_16x16x32_bf16(fal, fbh[nt], acc[mt][nt], 0, 0, 0);
        }
      }
    }
    // normal write (upper block)
#pragma unroll
    for (int mt = 0; mt < 4; ++mt)
#pragma unroll
      for (int nt = 0; nt < 4; ++nt) {
        int cg = n0 + wn + nt * 16 + r16;
        int rb = m0 + wm + mt * 16 + quad * 4;
#pragma unroll
        for (int r = 0; r < 4; ++r)
          Cb[(size_t)(rb + r) * SEQ + cg] = acc[mt][nt][r] * 0.0625f;
      }
    // mirror write (lower block): element (rb+r, cg) -> (cg, rb+r).
    // reg index r spans 4 consecutive COLUMNS of the mirror -> float4/lane.
    if (bi != bj) {
#pragma unroll
      for (int mt = 0; mt < 4; ++mt)
#pragma unroll
        for (int nt = 0; nt < 4; ++nt) {
          int cg = n0 + wn + nt * 16 + r16;
          int rb = m0 + wm + mt * 16 + quad * 4;
          float4 o;
          o.x = acc[mt][nt][0] * 0.0625f;
          o.y = acc[mt][nt][1] * 0.0625f;
          o.z = acc[mt][nt][2] * 0.0625f;
          o.w = acc[mt][nt][3] * 0.0625f;
          *(float4*)&Cb[(size_t)cg * SEQ + rb] = o;
        }
    }
  } else {
    // ----- qkv path -----
    const int j = lin - 544;
    const int m0 = (j & 63) * 128, n0 = ((j >> 6) & 1) * 128;
    const int z = j >> 7;
    const u16* Wh = wpk + (size_t)z * 2 * 65536;
    const u16* Wl = Wh + 65536;
    const float* bias = (z == 0) ? bq : (z == 1) ? bk : bv;
    u16* out = (z == 0) ? qo : (z == 1) ? ko : vo;
    for (int k0 = 0; k0 < EMB; k0 += 32) {
      __syncthreads();
      {
        size_t ga = (size_t)(m0 + srow) * EMB + k0 + shalf;
        size_t gb = (size_t)(n0 + srow) * EMB + k0 + shalf;
        uint4 ah0 = *(const uint4*)(xh + ga), ah1 = *(const uint4*)(xh + ga + 8);
        uint4 al0 = *(const uint4*)(xl + ga), al1 = *(const uint4*)(xl + ga + 8);
        uint4 bh0 = *(const uint4*)(Wh + gb), bh1 = *(const uint4*)(Wh + gb + 8);
        uint4 bl0 = *(const uint4*)(Wl + gb), bl1 = *(const uint4*)(Wl + gb + 8);
        int o = srow * 40 + shalf;
        *(uint4*)&Ah[o] = ah0; *(uint4*)&Ah[o + 8] = ah1;
        *(uint4*)&Al[o] = al0; *(uint4*)&Al[o + 8] = al1;
        *(uint4*)&Bh[o] = bh0; *(uint4*)&Bh[o + 8] = bh1;
        *(uint4*)&Bl[o] = bl0; *(uint4*)&Bl[o + 8] = bl1;
      }
      __syncthreads();
      frag8 fbh[4], fbl[4];
#pragma unroll
      for (int nt = 0; nt < 4; ++nt) {
        int ob = (wn + nt * 16 + r16) * 40 + quad * 8;
        fbh[nt] = *(const frag8*)&Bh[ob];
        fbl[nt] = *(const frag8*)&Bl[ob];
      }
#pragma unroll
      for (int mt = 0; mt < 4; ++mt) {
        int oa = (wm + mt * 16 + r16) * 40 + quad * 8;
        frag8 fah = *(const frag8*)&Ah[oa];
        frag8 fal = *(const frag8*)&Al[oa];
#pragma unroll
        for (int nt = 0; nt < 4; ++nt) {
          acc[mt][nt] = __builtin_amdgcn_mfma_f32_16x16x32_bf16(fah, fbh[nt], acc[mt][nt], 0, 0, 0);
          acc[mt][nt] = __builtin_amdgcn_mfma_f32_16x16x32_bf16(fah, fbl[nt], acc[mt][nt], 0, 0, 0);
          acc[mt][nt] = __builtin_amdgcn_mfma_f32_16x16x32_bf16(fal, fbh[nt], acc[mt][nt], 0, 0, 0);
        }
      }
    }
#pragma unroll
    for (int nt = 0; nt < 4; ++nt) {
      int cg = n0 + wn + nt * 16 + r16;
      float bvv = bias[cg];
#pragma unroll
      for (int mt = 0; mt < 4; ++mt) {
        int rb = m0 + wm + mt * 16 + quad * 4;
#pragma unroll
        for (int r = 0; r < 4; ++r) {
          HU hu; hu.h = (f16)(acc[mt][nt][r] + bvv);
          out[(size_t)(rb + r) * EMB + cg] = hu.u;
        }
      }
    }
  }
}

// ---------------------------------------------------------------------------
// Out projection: stages fp32 ctx, splits hi/lo in-kernel (3-term MFMA).
// ---------------------------------------------------------------------------
__global__ __launch_bounds__(256) void out_mfma(
    const float* __restrict__ ctx, const u16* __restrict__ wpk,
    const float* __restrict__ bias, float* __restrict__ out)
{
  const u16* Wh = wpk + (size_t)3 * 2 * 65536;
  const u16* Wl = Wh + 65536;
  __shared__ u16 Ah[128 * 40], Al[128 * 40], Bh[128 * 40], Bl[128 * 40];
  const int tid = threadIdx.x;
  const int m0 = blockIdx.x * 128, n0 = blockIdx.y * 128;
  const int wv = tid >> 6, ln = tid & 63;
  const int quad = ln >> 4, r16 = ln & 15;
  const int wm = (wv & 1) * 64, wn = (wv >> 1) * 64;
  const int srow = tid >> 1, shalf = (tid & 1) * 16;

  f32x4v acc[4][4];
#pragma unroll
  for (int i = 0; i < 4; ++i)
#pragma unroll
    for (int j = 0; j < 4; ++j) acc[i][j] = (f32x4v){0.f, 0.f, 0.f, 0.f};

  for (int k0 = 0; k0 < EMB; k0 += 32) {
    __syncthreads();
    {
      size_t ga = (size_t)(m0 + srow) * EMB + k0 + shalf;
      float4 c0 = *(const float4*)(ctx + ga);
      float4 c1 = *(const float4*)(ctx + ga + 4);
      float4 c2 = *(const float4*)(ctx + ga + 8);
      float4 c3 = *(const float4*)(ctx + ga + 12);
      float v[16] = {c0.x,c0.y,c0.z,c0.w, c1.x,c1.y,c1.z,c1.w,
                     c2.x,c2.y,c2.z,c2.w, c3.x,c3.y,c3.z,c3.w};
      u16 hh[16], ll[16];
#pragma unroll
      for (int jj = 0; jj < 16; ++jj) {
        hh[jj] = f2bf(v[jj]);
        ll[jj] = f2bf(v[jj] - bf2f(hh[jj]));
      }
      int o = srow * 40 + shalf;
#pragma unroll
      for (int g = 0; g < 2; ++g) {
        uint4 ph, pl;
        ph.x = hh[g*8+0] | ((unsigned)hh[g*8+1] << 16);
        ph.y = hh[g*8+2] | ((unsigned)hh[g*8+3] << 16);
        ph.z = hh[g*8+4] | ((unsigned)hh[g*8+5] << 16);
        ph.w = hh[g*8+6] | ((unsigned)hh[g*8+7] << 16);
        pl.x = ll[g*8+0] | ((unsigned)ll[g*8+1] << 16);
        pl.y = ll[g*8+2] | ((unsigned)ll[g*8+3] << 16);
        pl.z = ll[g*8+4] | ((unsigned)ll[g*8+5] << 16);
        pl.w = ll[g*8+6] | ((unsigned)ll[g*8+7] << 16);
        *(uint4*)&Ah[o + g*8] = ph;
        *(uint4*)&Al[o + g*8] = pl;
      }
      size_t gb = (size_t)(n0 + srow) * EMB + k0 + shalf;
      uint4 bh0 = *(const uint4*)(Wh + gb), bh1 = *(const uint4*)(Wh + gb + 8);
      uint4 bl0 = *(const uint4*)(Wl + gb), bl1 = *(const uint4*)(Wl + gb + 8);
      *(uint4*)&Bh[o] = bh0; *(uint4*)&Bh[o + 8] = bh1;
      *(uint4*)&Bl[o] = bl0; *(uint4*)&Bl[o + 8] = bl1;
    }
    __syncthreads();
    frag8 fbh[4], fbl[4];
#pragma unroll
    for (int nt = 0; nt < 4; ++nt) {
      int ob = (wn + nt * 16 + r16) * 40 + quad * 8;
      fbh[nt] = *(const frag8*)&Bh[ob];
      fbl[nt] = *(const frag8*)&Bl[ob];
    }
#pragma unroll
    for (int mt = 0; mt < 4; ++mt) {
      int oa = (wm + mt * 16 + r16) * 40 + quad * 8;
      frag8 fah = *(const frag8*)&Ah[oa];
      frag8 fal = *(const frag8*)&Al[oa];
#pragma unroll
      for (int nt = 0; nt < 4; ++nt) {
        acc[mt][nt] = __builtin_amdgcn_mfma_f32_16x16x32_bf16(fah, fbh[nt], acc[mt][nt], 0, 0, 0);
        acc[mt][nt] = __builtin_amdgcn_mfma_f32_16x16x32_bf16(fah, fbl[nt], acc[mt][nt], 0, 0, 0);
        acc[mt][nt] = __builtin_amdgcn_mfma_f32_16x16x32_bf16(fal, fbh[nt], acc[mt][nt], 0, 0, 0);
      }
    }
  }
#pragma unroll
  for (int nt = 0; nt < 4; ++nt) {
    int cg = n0 + wn + nt * 16 + r16;
    float bvv = bias[cg];
#pragma unroll
    for (int mt = 0; mt < 4; ++mt) {
      int rb = m0 + wm + mt * 16 + quad * 4;
#pragma unroll
      for (int r = 0; r < 4; ++r)
        out[(size_t)(rb + r) * EMB + cg] = acc[mt][nt][r] + bvv;
    }
  }
}

// ---------------------------------------------------------------------------
// Top-k per row (radix-256), with margin flagging into per-batch lists.
// ---------------------------------------------------------------------------
__global__ __launch_bounds__(256) void topk_idx(
    const float* __restrict__ scores, u16* __restrict__ idxl,
    int* __restrict__ flagcnt, int* __restrict__ flaglist)
{
  __shared__ int hist[4][256];
  __shared__ int sel[2];
  __shared__ int wsum[4];
  __shared__ unsigned wmax[4];
  const int r = blockIdx.x;
  const int tid = threadIdx.x;
  const int lane = tid & 63, wid = tid >> 6;
  const float* row = scores + (size_t)r * SEQ;
  unsigned key[8];
  {
    float4 f0 = *(const float4*)(row + tid * 8);
    float4 f1 = *(const float4*)(row + tid * 8 + 4);
    key[0]=f2ord(f0.x); key[1]=f2ord(f0.y); key[2]=f2ord(f0.z); key[3]=f2ord(f0.w);
    key[4]=f2ord(f1.x); key[5]=f2ord(f1.y); key[6]=f2ord(f1.z); key[7]=f2ord(f1.w);
  }
  unsigned V; int MEQ;
  tk_radix(key, tid, hist, sel, V, MEQ);

  {
    int ceq = 0; unsigned mk = 0;
#pragma unroll
    for (int j = 0; j < 8; ++j) {
      ceq += (key[j] == V) ? 1 : 0;
      if (key[j] < V && key[j] > mk) mk = key[j];
    }
#pragma unroll
    for (int off = 32; off > 0; off >>= 1) {
      ceq += __shfl_down(ceq, off, 64);
      unsigned o = (unsigned)__shfl_down((int)mk, off, 64);
      if (o > mk) mk = o;
    }
    if (lane == 0) { wsum[wid] = ceq; wmax[wid] = mk; }
    __syncthreads();
    if (tid == 0) {
      int EQ = wsum[0] + wsum[1] + wsum[2] + wsum[3];
      unsigned m2 = wmax[0];
      for (int w = 1; w < 4; ++w) if (wmax[w] > m2) m2 = wmax[w];
      bool flag = (EQ > MEQ) || !(ord2f(V) - ord2f(m2) >= MBOUND);
      if (flag) {
        int bb = r >> 11;
        int p = atomicAdd(&flagcnt[bb], 1);
        flaglist[bb * SEQ + p] = r & (SEQ - 1);
      }
    }
    __syncthreads();
  }

  tk_write(key, V, MEQ, tid, idxl + (size_t)r * IDXP, wsum);
}

// ---------------------------------------------------------------------------
// Fixup A: exact fp32 scores for flagged rows (gathered-A 64x64 GEMM).
// ---------------------------------------------------------------------------
__global__ __launch_bounds__(256) void fixup_gemm(
    const float* __restrict__ x, const int* __restrict__ flagcnt,
    const int* __restrict__ flaglist, float* __restrict__ attn)
{
  const int b = blockIdx.z;
  const int n = flagcnt[b];
  const int g0 = blockIdx.y * 64;
  if (g0 >= n) return;
  __shared__ float As[16][68];
  __shared__ float Bs[16][68];
  __shared__ int rowsh[64];
  const int tid = threadIdx.x;
  const int n0 = blockIdx.x * 64;
  if (tid < 64) {
    int gi = g0 + tid;
    rowsh[tid] = (gi < n) ? flaglist[b * SEQ + gi] : -1;
  }
  __syncthreads();
  const float* xb = x + (size_t)b * SEQ * EMB;
  const int lm = tid >> 2;
  const int lk = (tid & 3) << 2;
  const int mt = tid >> 4;
  const int nt = tid & 15;
  const int arow = rowsh[lm];
  const int arowL = (arow < 0) ? 0 : arow;
  float acc[4][4] = {{0.f}};
  for (int k0 = 0; k0 < EMB; k0 += 16) {
    float4 av = *(const float4*)(xb + (size_t)arowL * EMB + k0 + lk);
    float4 bv = *(const float4*)(xb + (size_t)(n0 + lm) * EMB + k0 + lk);
    __syncthreads();
    As[lk+0][lm] = av.x; As[lk+1][lm] = av.y; As[lk+2][lm] = av.z; As[lk+3][lm] = av.w;
    Bs[lk+0][lm] = bv.x; Bs[lk+1][lm] = bv.y; Bs[lk+2][lm] = bv.z; Bs[lk+3][lm] = bv.w;
    __syncthreads();
#pragma unroll
    for (int kk = 0; kk < 16; ++kk) {
      float4 a4 = *(const float4*)&As[kk][mt << 2];
      float4 b4 = *(const float4*)&Bs[kk][nt << 2];
      acc[0][0] += a4.x*b4.x; acc[0][1] += a4.x*b4.y; acc[0][2] += a4.x*b4.z; acc[0][3] += a4.x*b4.w;
      acc[1][0] += a4.y*b4.x; acc[1][1] += a4.y*b4.y; acc[1][2] += a4.y*b4.z; acc[1][3] += a4.y*b4.w;
      acc[2][0] += a4.z*b4.x; acc[2][1] += a4.z*b4.y; acc[2][2] += a4.z*b4.z; acc[2][3] += a4.z*b4.w;
      acc[3][0] += a4.w*b4.x; acc[3][1] += a4.w*b4.y; acc[3][2] += a4.w*b4.z; acc[3][3] += a4.w*b4.w;
    }
  }
  float* attnB = attn + (size_t)b * SEQ * SEQ;
#pragma unroll
  for (int r = 0; r < 4; ++r) {
    int rr = rowsh[(mt << 2) + r];
    if (rr >= 0) {
      float4 o;
      o.x = acc[r][0] * 0.0625f; o.y = acc[r][1] * 0.0625f;
      o.z = acc[r][2] * 0.0625f; o.w = acc[r][3] * 0.0625f;
      *(float4*)(attnB + (size_t)rr * SEQ + n0 + (nt << 2)) = o;
    }
  }
}

// ---------------------------------------------------------------------------
// Fixup B: redo top-k (radix) on the now-exact flagged rows.
// ---------------------------------------------------------------------------
__global__ __launch_bounds__(256) void topk_fixup(
    const float* __restrict__ attn, const int* __restrict__ flagcnt,
    const int* __restrict__ flaglist, u16* __restrict__ idxl)
{
  const int b = blockIdx.y;
  if ((int)blockIdx.x >= flagcnt[b]) return;
  const int r = b * SEQ + flaglist[b * SEQ + blockIdx.x];
  __shared__ int hist[4][256];
  __shared__ int sel[2];
  __shared__ int wsum[4];
  const int tid = threadIdx.x;
  const float* row = attn + (size_t)r * SEQ;
  unsigned key[8];
  {
    float4 f0 = *(const float4*)(row + tid * 8);
    float4 f1 = *(const float4*)(row + tid * 8 + 4);
    key[0]=f2ord(f0.x); key[1]=f2ord(f0.y); key[2]=f2ord(f0.z); key[3]=f2ord(f0.w);
    key[4]=f2ord(f1.x); key[5]=f2ord(f1.y); key[6]=f2ord(f1.z); key[7]=f2ord(f1.w);
  }
  unsigned V; int MEQ;
  tk_radix(key, tid, hist, sel, V, MEQ);
  tk_write(key, V, MEQ, tid, idxl + (size_t)r * IDXP, wsum);
}

// ---------------------------------------------------------------------------
// Sparse attention v6 (REVERTED from fused v7): two-pass structure keeps
// VGPR at 24 -> 8 waves/SIMD. The v7 single-pass fusion raised VGPR to 84
// (4-deep unroll holding K+V gathers live across the dot->shfl->exp chain),
// halving occupancy and costing +40% (85.6 -> 119.5 us, measured R3).
// TLP > ILP for this gather-latency-bound kernel.
// ---------------------------------------------------------------------------
__global__ __launch_bounds__(256) void sparse_attn(
    const u16* __restrict__ qf, const u16* __restrict__ kf,
    const u16* __restrict__ vf, const u16* __restrict__ idxl,
    float* __restrict__ attn, float* __restrict__ ctxb)
{
  const int lin = blockIdx.x;
  const int b = lin & 3;                                  // XCD-stable batch
  const int q = (lin >> 3) + (((lin >> 2) & 1) << 10);
  const int tid = threadIdx.x;
  const int wv = tid >> 6, ln = tid & 63;
  const int half = ln >> 5, sl = ln & 31;
  const int h = sl >> 2, d0 = sl * 8;
  const int lb = sl * 16;
  __shared__ int   ish[IDXP];
  __shared__ int   koff[IDXP];
  __shared__ float psh[IDXP * 9 + 4];   // [j][h], stride 9
  __shared__ float idsh[NH];
  __shared__ float rcsh[2112];          // union: rsh[2048] | csh[8][264]
#define CSH(i, j) rcsh[(i) * 264 + (j)]

  const int row = b * SEQ + q;
  if (tid < KTOP) {
    int idx = (int)idxl[(size_t)row * IDXP + tid];
    ish[tid] = idx;
    koff[tid] = idx << 9;
  } else if (tid < IDXP) {
    ish[tid] = 0; koff[tid] = 0;
  }
  if (tid < 32) psh[(KTOP + (tid >> 3)) * 9 + (tid & 7)] = 0.f;

  float4 z4 = make_float4(0.f, 0.f, 0.f, 0.f);
  *(float4*)&rcsh[tid * 4]        = z4;
  *(float4*)&rcsh[1024 + tid * 4] = z4;

  U4 qv;
  qv.u = *(const uint4*)((const char*)(qf + (size_t)row * EMB) + lb);

  __syncthreads();

  const float scale = 0.17677669529663687f;  // 1/sqrt(32)
  const char* kbC = (const char*)(kf + (size_t)(b * SEQ) * EMB);
  const int jb = wv * KPW;
#pragma unroll 4
  for (int t = 0; t < KPW; t += 2) {
    const int j = jb + t + half;
    U4 kv;
    kv.u = *(const uint4*)(kbC + (koff[j] + lb));
    float s = FDOT2(qv.h[0], kv.h[0],
              FDOT2(qv.h[1], kv.h[1],
              FDOT2(qv.h[2], kv.h[2],
              FDOT2(qv.h[3], kv.h[3], 0.f))));
    s += __shfl_xor(s, 1, 64);
    s += __shfl_xor(s, 2, 64);
    if ((sl & 3) == 0 && j < KTOP) psh[j * 9 + h] = __expf(s * scale);
  }
  __syncthreads();

  {
    int h2 = tid >> 5, l = tid & 31;
    float sden = 0.f;
    for (int j = l; j < KTOP; j += 32) sden += psh[j * 9 + h2];
#pragma unroll
    for (int off = 16; off > 0; off >>= 1) sden += __shfl_down(sden, off, 32);
    if (l == 0) idsh[h2] = 1.0f / sden;
  }
  __syncthreads();

  if (tid < KTOP) {
    float ps = 0.f;
#pragma unroll
    for (int hh = 0; hh < 8; ++hh) {
      float pp = psh[tid * 9 + hh] * idsh[hh];
      psh[tid * 9 + hh] = pp;
      ps += pp;
    }
    rcsh[ish[tid]] = ps * 0.125f;
  }
  __syncthreads();

  // stream dense row out (full-line, conflict-free)
  {
    float* arow = attn + (size_t)row * SEQ;
    *(float4*)(arow + tid * 4)        = *(const float4*)&rcsh[tid * 4];
    *(float4*)(arow + 1024 + tid * 4) = *(const float4*)&rcsh[1024 + tid * 4];
  }
  __syncthreads();   // rsh dead; csh may now overwrite the region

  {
    const char* vbC = (const char*)(vf + (size_t)(b * SEQ) * EMB);
    float a8[8] = {0.f,0.f,0.f,0.f,0.f,0.f,0.f,0.f};
#pragma unroll 4
    for (int t = 0; t < KPW; t += 2) {
      const int j = jb + t + half;
      float p = psh[j * 9 + h];
      U4 vv;
      vv.u = *(const uint4*)(vbC + (koff[j] + lb));
      a8[0] += p * (float)vv.h[0][0]; a8[1] += p * (float)vv.h[0][1];
      a8[2] += p * (float)vv.h[1][0]; a8[3] += p * (float)vv.h[1][1];
      a8[4] += p * (float)vv.h[2][0]; a8[5] += p * (float)vv.h[2][1];
      a8[6] += p * (float)vv.h[3][0]; a8[7] += p * (float)vv.h[3][1];
    }
    const int pi = wv * 2 + half;
    *(float4*)&CSH(pi, d0)     = make_float4(a8[0], a8[1], a8[2], a8[3]);
    *(float4*)&CSH(pi, d0 + 4) = make_float4(a8[4], a8[5], a8[6], a8[7]);
  }
  __syncthreads();
  if (tid < 64) {
    float4 o = z4;
#pragma unroll
    for (int g = 0; g < 8; ++g) {
      float4 v = *(const float4*)&CSH(g, tid * 4);
      o.x += v.x; o.y += v.y; o.z += v.z; o.w += v.w;
    }
    *(float4*)(ctxb + (size_t)row * EMB + tid * 4) = o;
  }
#undef CSH
}

// ---------------------------------------------------------------------------
extern "C" void kernel_launch(void* const* d_in, const int* in_sizes, int n_in,
                              void* d_out, int out_size, void* d_ws, size_t ws_size,
                              hipStream_t stream)
{
  const float* x  = (const float*)d_in[0];
  const float* Wq = (const float*)d_in[1];
  const float* bq = (const float*)d_in[2];
  const float* Wk = (const float*)d_in[3];
  const float* bk = (const float*)d_in[4];
  const float* Wv = (const float*)d_in[5];
  const float* bv = (const float*)d_in[6];
  const float* Wo = (const float*)d_in[7];
  const float* bo = (const float*)d_in[8];

  float* out  = (float*)d_out;
  float* attn = out + (size_t)NB * SEQ * EMB;   // [B,S,S] region of d_out

  const size_t NSE = (size_t)NB * SEQ * EMB;    // 2097152
  u16* xh  = (u16*)d_ws;            // bf16 hi of x
  u16* xl  = xh + NSE;              // bf16 lo
  u16* qf  = xl + NSE;              // f16 Q
  u16* kf  = qf + NSE;              // f16 K
  u16* vf  = kf + NSE;              // f16 V
  u16* wpk = vf + NSE;              // 4 x (hi,lo) 256x256 bf16
  float* ctxb = (float*)(wpk + 4 * 2 * 65536);
  u16* idxl = (u16*)(ctxb + NSE);
  int* flagcnt  = (int*)(idxl + (size_t)NB * SEQ * IDXP);
  int* flaglist = flagcnt + NB;

  const dim3 blk(256);

  // hi/lo splits of x + weights (one launch); flag counters reset
  pack_all<<<dim3(1152), blk, 0, stream>>>(x, Wq, Wk, Wv, Wo, xh, xl, wpk, flagcnt);

  // symmetric scores (544 upper-triangle blocks) + QKV (384) in one launch
  fused_gemms<<<dim3(928), blk, 0, stream>>>(xh, xl, wpk, bq, bk, bv,
                                             qf, kf, vf, attn);

  // radix top-k with margin flagging; exact fp32 fixup of low-margin rows
  topk_idx<<<dim3(NB * SEQ), blk, 0, stream>>>(attn, idxl, flagcnt, flaglist);
  fixup_gemm<<<dim3(32, 32, NB), blk, 0, stream>>>(x, flagcnt, flaglist, attn);
  topk_fixup<<<dim3(SEQ, NB), blk, 0, stream>>>(attn, flagcnt, flaglist, idxl);

  // fused sparse attention (f16 gathers + fdot2, shared rsh/csh LDS)
  sparse_attn<<<dim3(SEQ * NB), blk, 0, stream>>>(qf, kf, vf, idxl, attn, ctxb);

  // out = ctx @ Wo^T + bo (in-kernel hi/lo split of ctx)
  out_mfma<<<dim3(64, 2), blk, 0, stream>>>(ctxb, wpk, bo, out);
}

// Round 5
// 319.564 us; speedup vs baseline: 1.0960x; 1.0155x over previous
//
#include <hip/hip_runtime.h>

#define SEQ  2048
#define EMB  256
#define NH   8
#define HD   32
#define NB   4
#define KTOP 204
#define IDXP 208
#define KPW  52       // keys per wave (4*52 = 208, padded)
#define MBOUND 4e-4f  // top-k margin for fp32 re-verify

typedef unsigned long long ull;
typedef unsigned short u16;

using frag8  = __attribute__((ext_vector_type(8))) short;  // 8 bf16
using f32x4v = __attribute__((ext_vector_type(4))) float;
typedef _Float16 f16;
typedef _Float16 f16x2 __attribute__((ext_vector_type(2)));

union U4 { uint4 u; f16x2 h[4]; };
union HU { f16 h; u16 u; };

#if defined(__has_builtin)
#if __has_builtin(__builtin_amdgcn_fdot2)
#define FDOT2(a,b,c) __builtin_amdgcn_fdot2(a, b, c, false)
#endif
#endif
#ifndef FDOT2
__device__ __forceinline__ float fdot2_sw(f16x2 a, f16x2 b, float c) {
  return c + (float)a[0]*(float)b[0] + (float)a[1]*(float)b[1];
}
#define FDOT2(a,b,c) fdot2_sw(a,b,c)
#endif

__device__ __forceinline__ unsigned f2ord(float f) {
  unsigned u = __float_as_uint(f);
  return (u & 0x80000000u) ? ~u : (u | 0x80000000u);
}
__device__ __forceinline__ float ord2f(unsigned o) {
  unsigned u = (o & 0x80000000u) ? (o ^ 0x80000000u) : ~o;
  return __uint_as_float(u);
}
__device__ __forceinline__ u16 f2bf(float f) {
  unsigned u = __float_as_uint(f);
  u += 0x7FFF + ((u >> 16) & 1);     // RTNE
  return (u16)(u >> 16);
}
__device__ __forceinline__ float bf2f(u16 h) {
  return __uint_as_float((unsigned)h << 16);
}

// ---------------------------------------------------------------------------
// Radix-256 top-k (4 byte passes, per-wave histograms, wave-0 suffix scan).
// ---------------------------------------------------------------------------
__device__ __forceinline__ void tk_radix(
    const unsigned key[8], int tid, int (*hist)[256], int* sel,
    unsigned& V, int& MEQ)
{
  const int lane = tid & 63, wid = tid >> 6;
  unsigned prefix = 0;
  int k = KTOP;
#pragma unroll
  for (int p = 0; p < 4; ++p) {
    const int shift = 24 - 8 * p;
    hist[0][tid] = 0; hist[1][tid] = 0; hist[2][tid] = 0; hist[3][tid] = 0;
    __syncthreads();
#pragma unroll
    for (int j = 0; j < 8; ++j) {
      unsigned kj = key[j];
      bool ok = (p == 0) || ((kj >> (shift + 8)) == prefix);
      if (ok) atomicAdd(&hist[wid][(kj >> shift) & 255], 1);
    }
    __syncthreads();
    {
      int c = hist[0][tid] + hist[1][tid] + hist[2][tid] + hist[3][tid];
      hist[0][tid] = c;
    }
    __syncthreads();
    if (wid == 0) {
      int m0 = hist[0][lane * 4 + 0], m1 = hist[0][lane * 4 + 1];
      int m2 = hist[0][lane * 4 + 2], m3 = hist[0][lane * 4 + 3];
      int sl = m0 + m1 + m2 + m3;
      int suf = sl;
#pragma unroll
      for (int off = 1; off < 64; off <<= 1) {
        int y = __shfl_down(suf, off, 64);
        if (lane + off < 64) suf += y;
      }
      int above = suf - sl;
      if (above < k && k <= suf) {
        int bin, nk;
        if (k <= above + m3)                { bin = lane*4+3; nk = k - above; }
        else if (k <= above + m3 + m2)      { bin = lane*4+2; nk = k - above - m3; }
        else if (k <= above + m3 + m2 + m1) { bin = lane*4+1; nk = k - above - m3 - m2; }
        else                                { bin = lane*4+0; nk = k - above - m3 - m2 - m1; }
        sel[0] = bin; sel[1] = nk;
      }
    }
    __syncthreads();
    prefix = (prefix << 8) | (unsigned)sel[0];
    k = sel[1];
    __syncthreads();
  }
  V = prefix;
  MEQ = k;
}

__device__ __forceinline__ int tk_scan_excl(int v, int tid, int* wsum) {
  const int lane = tid & 63, wid = tid >> 6;
  int x = v;
#pragma unroll
  for (int off = 1; off < 64; off <<= 1) {
    int y = __shfl_up(x, off, 64);
    if (lane >= off) x += y;
  }
  if (lane == 63) wsum[wid] = x;
  __syncthreads();
  int base = 0;
  for (int w = 0; w < wid; ++w) base += wsum[w];
  return base + x - v;
}

__device__ __forceinline__ void tk_write(const unsigned key[8], unsigned V, int MEQ,
                                         int tid, u16* orow, int* wsum) {
  int ceq = 0;
#pragma unroll
  for (int j = 0; j < 8; ++j) ceq += (key[j] == V) ? 1 : 0;
  int run = tk_scan_excl(ceq, tid, wsum);
  unsigned bits = 0;
#pragma unroll
  for (int j = 0; j < 8; ++j) {
    bool e = (key[j] == V);
    bool s = (key[j] > V) || (e && (run < MEQ));
    if (e) run++;
    if (s) bits |= (1u << j);
  }
  int csel = __popc(bits);
  __syncthreads();
  int base = tk_scan_excl(csel, tid, wsum);
#pragma unroll
  for (int j = 0; j < 8; ++j)
    if ((bits >> j) & 1u) orow[base++] = (u16)(tid * 8 + j);
}

// ---------------------------------------------------------------------------
// pack_all: bf16 hi/lo split of x (blocks 0..1023) and the 4 weight matrices
// (blocks 1024..1151); block 0 also zeroes the per-batch flag counters.
// ---------------------------------------------------------------------------
__global__ __launch_bounds__(256) void pack_all(
    const float* __restrict__ x,
    const float* __restrict__ W0, const float* __restrict__ W1,
    const float* __restrict__ W2, const float* __restrict__ W3,
    u16* __restrict__ xh, u16* __restrict__ xl, u16* __restrict__ wpk,
    int* __restrict__ flagcnt)
{
  const int lin = blockIdx.x;
  if (lin == 0 && threadIdx.x < NB) flagcnt[threadIdx.x] = 0;
  const float* src; u16 *dh, *dl; int i;
  if (lin < 1024) {
    src = x;
    i = (lin * 256 + threadIdx.x) * 8;
    dh = xh; dl = xl;
  } else {
    int j = lin - 1024;             // 0..127
    int m = j >> 5, bx = j & 31;
    src = (m == 0) ? W0 : (m == 1) ? W1 : (m == 2) ? W2 : W3;
    i = (bx * 256 + threadIdx.x) * 8;
    dh = wpk + (size_t)m * 2 * 65536;
    dl = dh + 65536;
  }
  float4 a = *(const float4*)(src + i);
  float4 b = *(const float4*)(src + i + 4);
  float v[8] = {a.x,a.y,a.z,a.w,b.x,b.y,b.z,b.w};
  u16 h[8], l[8];
#pragma unroll
  for (int j = 0; j < 8; ++j) {
    h[j] = f2bf(v[j]);
    l[j] = f2bf(v[j] - bf2f(h[j]));
  }
  uint4 ph, pl;
  ph.x = h[0] | ((unsigned)h[1] << 16); ph.y = h[2] | ((unsigned)h[3] << 16);
  ph.z = h[4] | ((unsigned)h[5] << 16); ph.w = h[6] | ((unsigned)h[7] << 16);
  pl.x = l[0] | ((unsigned)l[1] << 16); pl.y = l[2] | ((unsigned)l[3] << 16);
  pl.z = l[4] | ((unsigned)l[5] << 16); pl.w = l[6] | ((unsigned)l[7] << 16);
  *(uint4*)(dh + i) = ph;
  *(uint4*)(dl + i) = pl;
}

// ---------------------------------------------------------------------------
// fused_gemms: scores (SYMMETRIC — upper-triangle blocks only, mirror written
// from registers; blocks 0..543) + QKV projections (blocks 544..927).
// Scores use 3-term hi/lo MFMA (lo*lo dropped): adds ~3e-6 score error,
// 100x below MBOUND=4e-4, and scores only feed margin-guarded top-k.
// ---------------------------------------------------------------------------
__global__ __launch_bounds__(256) void fused_gemms(
    const u16* __restrict__ xh, const u16* __restrict__ xl,
    const u16* __restrict__ wpk,
    const float* __restrict__ bq, const float* __restrict__ bk,
    const float* __restrict__ bv,
    u16* __restrict__ qo, u16* __restrict__ ko, u16* __restrict__ vo,
    float* __restrict__ attnC)
{
  __shared__ u16 Ah[128 * 40], Al[128 * 40], Bh[128 * 40], Bl[128 * 40];
  const int lin = blockIdx.x;
  const int tid = threadIdx.x;
  const int wv = tid >> 6, ln = tid & 63;
  const int quad = ln >> 4, r16 = ln & 15;
  const int wm = (wv & 1) * 64, wn = (wv >> 1) * 64;
  const int srow = tid >> 1, shalf = (tid & 1) * 16;

  f32x4v acc[4][4];
#pragma unroll
  for (int i = 0; i < 4; ++i)
#pragma unroll
    for (int j = 0; j < 4; ++j) acc[i][j] = (f32x4v){0.f, 0.f, 0.f, 0.f};

  if (lin < 544) {
    // ----- scores path (symmetric, bi <= bj) -----
    const int b = lin / 136;
    int p = lin - b * 136;
    int bi = 0;
    while (p >= 16 - bi) { p -= 16 - bi; ++bi; }
    const int bj = bi + p;
    const int m0 = bi * 128, n0 = bj * 128;
    const u16* xhB = xh + (size_t)b * SEQ * EMB;
    const u16* xlB = xl + (size_t)b * SEQ * EMB;
    float* Cb = attnC + (size_t)b * SEQ * SEQ;
    for (int k0 = 0; k0 < EMB; k0 += 32) {
      __syncthreads();
      {
        size_t ga = (size_t)(m0 + srow) * EMB + k0 + shalf;
        size_t gb = (size_t)(n0 + srow) * EMB + k0 + shalf;
        uint4 ah0 = *(const uint4*)(xhB + ga), ah1 = *(const uint4*)(xhB + ga + 8);
        uint4 al0 = *(const uint4*)(xlB + ga), al1 = *(const uint4*)(xlB + ga + 8);
        uint4 bh0 = *(const uint4*)(xhB + gb), bh1 = *(const uint4*)(xhB + gb + 8);
        uint4 bl0 = *(const uint4*)(xlB + gb), bl1 = *(const uint4*)(xlB + gb + 8);
        int o = srow * 40 + shalf;
        *(uint4*)&Ah[o] = ah0; *(uint4*)&Ah[o + 8] = ah1;
        *(uint4*)&Al[o] = al0; *(uint4*)&Al[o + 8] = al1;
        *(uint4*)&Bh[o] = bh0; *(uint4*)&Bh[o + 8] = bh1;
        *(uint4*)&Bl[o] = bl0; *(uint4*)&Bl[o + 8] = bl1;
      }
      __syncthreads();
      frag8 fbh[4], fbl[4];
#pragma unroll
      for (int nt = 0; nt < 4; ++nt) {
        int ob = (wn + nt * 16 + r16) * 40 + quad * 8;
        fbh[nt] = *(const frag8*)&Bh[ob];
        fbl[nt] = *(const frag8*)&Bl[ob];
      }
#pragma unroll
      for (int mt = 0; mt < 4; ++mt) {
        int oa = (wm + mt * 16 + r16) * 40 + quad * 8;
        frag8 fah = *(const frag8*)&Ah[oa];
        frag8 fal = *(const frag8*)&Al[oa];
#pragma unroll
        for (int nt = 0; nt < 4; ++nt) {
          acc[mt][nt] = __builtin_amdgcn_mfma_f32_16x16x32_bf16(fah, fbh[nt], acc[mt][nt], 0, 0, 0);
          acc[mt][nt] = __builtin_amdgcn_mfma_f32_16x16x32_bf16(fah, fbl[nt], acc[mt][nt], 0, 0, 0);
          acc[mt][nt] = __builtin_amdgcn_mfma_f32_16x16x32_bf16(fal, fbh[nt], acc[mt][nt], 0, 0, 0);
        }
      }
    }
    // normal write (upper block)
#pragma unroll
    for (int mt = 0; mt < 4; ++mt)
#pragma unroll
      for (int nt = 0; nt < 4; ++nt) {
        int cg = n0 + wn + nt * 16 + r16;
        int rb = m0 + wm + mt * 16 + quad * 4;
#pragma unroll
        for (int r = 0; r < 4; ++r)
          Cb[(size_t)(rb + r) * SEQ + cg] = acc[mt][nt][r] * 0.0625f;
      }
    // mirror write (lower block): element (rb+r, cg) -> (cg, rb+r).
    // reg index r spans 4 consecutive COLUMNS of the mirror -> float4/lane.
    if (bi != bj) {
#pragma unroll
      for (int mt = 0; mt < 4; ++mt)
#pragma unroll
        for (int nt = 0; nt < 4; ++nt) {
          int cg = n0 + wn + nt * 16 + r16;
          int rb = m0 + wm + mt * 16 + quad * 4;
          float4 o;
          o.x = acc[mt][nt][0] * 0.0625f;
          o.y = acc[mt][nt][1] * 0.0625f;
          o.z = acc[mt][nt][2] * 0.0625f;
          o.w = acc[mt][nt][3] * 0.0625f;
          *(float4*)&Cb[(size_t)cg * SEQ + rb] = o;
        }
    }
  } else {
    // ----- qkv path -----
    const int j = lin - 544;
    const int m0 = (j & 63) * 128, n0 = ((j >> 6) & 1) * 128;
    const int z = j >> 7;
    const u16* Wh = wpk + (size_t)z * 2 * 65536;
    const u16* Wl = Wh + 65536;
    const float* bias = (z == 0) ? bq : (z == 1) ? bk : bv;
    u16* out = (z == 0) ? qo : (z == 1) ? ko : vo;
    for (int k0 = 0; k0 < EMB; k0 += 32) {
      __syncthreads();
      {
        size_t ga = (size_t)(m0 + srow) * EMB + k0 + shalf;
        size_t gb = (size_t)(n0 + srow) * EMB + k0 + shalf;
        uint4 ah0 = *(const uint4*)(xh + ga), ah1 = *(const uint4*)(xh + ga + 8);
        uint4 al0 = *(const uint4*)(xl + ga), al1 = *(const uint4*)(xl + ga + 8);
        uint4 bh0 = *(const uint4*)(Wh + gb), bh1 = *(const uint4*)(Wh + gb + 8);
        uint4 bl0 = *(const uint4*)(Wl + gb), bl1 = *(const uint4*)(Wl + gb + 8);
        int o = srow * 40 + shalf;
        *(uint4*)&Ah[o] = ah0; *(uint4*)&Ah[o + 8] = ah1;
        *(uint4*)&Al[o] = al0; *(uint4*)&Al[o + 8] = al1;
        *(uint4*)&Bh[o] = bh0; *(uint4*)&Bh[o + 8] = bh1;
        *(uint4*)&Bl[o] = bl0; *(uint4*)&Bl[o + 8] = bl1;
      }
      __syncthreads();
      frag8 fbh[4], fbl[4];
#pragma unroll
      for (int nt = 0; nt < 4; ++nt) {
        int ob = (wn + nt * 16 + r16) * 40 + quad * 8;
        fbh[nt] = *(const frag8*)&Bh[ob];
        fbl[nt] = *(const frag8*)&Bl[ob];
      }
#pragma unroll
      for (int mt = 0; mt < 4; ++mt) {
        int oa = (wm + mt * 16 + r16) * 40 + quad * 8;
        frag8 fah = *(const frag8*)&Ah[oa];
        frag8 fal = *(const frag8*)&Al[oa];
#pragma unroll
        for (int nt = 0; nt < 4; ++nt) {
          acc[mt][nt] = __builtin_amdgcn_mfma_f32_16x16x32_bf16(fah, fbh[nt], acc[mt][nt], 0, 0, 0);
          acc[mt][nt] = __builtin_amdgcn_mfma_f32_16x16x32_bf16(fah, fbl[nt], acc[mt][nt], 0, 0, 0);
          acc[mt][nt] = __builtin_amdgcn_mfma_f32_16x16x32_bf16(fal, fbh[nt], acc[mt][nt], 0, 0, 0);
        }
      }
    }
#pragma unroll
    for (int nt = 0; nt < 4; ++nt) {
      int cg = n0 + wn + nt * 16 + r16;
      float bvv = bias[cg];
#pragma unroll
      for (int mt = 0; mt < 4; ++mt) {
        int rb = m0 + wm + mt * 16 + quad * 4;
#pragma unroll
        for (int r = 0; r < 4; ++r) {
          HU hu; hu.h = (f16)(acc[mt][nt][r] + bvv);
          out[(size_t)(rb + r) * EMB + cg] = hu.u;
        }
      }
    }
  }
}

// ---------------------------------------------------------------------------
// Out projection: stages fp32 ctx, splits hi/lo in-kernel (3-term MFMA).
// ---------------------------------------------------------------------------
__global__ __launch_bounds__(256) void out_mfma(
    const float* __restrict__ ctx, const u16* __restrict__ wpk,
    const float* __restrict__ bias, float* __restrict__ out)
{
  const u16* Wh = wpk + (size_t)3 * 2 * 65536;
  const u16* Wl = Wh + 65536;
  __shared__ u16 Ah[128 * 40], Al[128 * 40], Bh[128 * 40], Bl[128 * 40];
  const int tid = threadIdx.x;
  const int m0 = blockIdx.x * 128, n0 = blockIdx.y * 128;
  const int wv = tid >> 6, ln = tid & 63;
  const int quad = ln >> 4, r16 = ln & 15;
  const int wm = (wv & 1) * 64, wn = (wv >> 1) * 64;
  const int srow = tid >> 1, shalf = (tid & 1) * 16;

  f32x4v acc[4][4];
#pragma unroll
  for (int i = 0; i < 4; ++i)
#pragma unroll
    for (int j = 0; j < 4; ++j) acc[i][j] = (f32x4v){0.f, 0.f, 0.f, 0.f};

  for (int k0 = 0; k0 < EMB; k0 += 32) {
    __syncthreads();
    {
      size_t ga = (size_t)(m0 + srow) * EMB + k0 + shalf;
      float4 c0 = *(const float4*)(ctx + ga);
      float4 c1 = *(const float4*)(ctx + ga + 4);
      float4 c2 = *(const float4*)(ctx + ga + 8);
      float4 c3 = *(const float4*)(ctx + ga + 12);
      float v[16] = {c0.x,c0.y,c0.z,c0.w, c1.x,c1.y,c1.z,c1.w,
                     c2.x,c2.y,c2.z,c2.w, c3.x,c3.y,c3.z,c3.w};
      u16 hh[16], ll[16];
#pragma unroll
      for (int jj = 0; jj < 16; ++jj) {
        hh[jj] = f2bf(v[jj]);
        ll[jj] = f2bf(v[jj] - bf2f(hh[jj]));
      }
      int o = srow * 40 + shalf;
#pragma unroll
      for (int g = 0; g < 2; ++g) {
        uint4 ph, pl;
        ph.x = hh[g*8+0] | ((unsigned)hh[g*8+1] << 16);
        ph.y = hh[g*8+2] | ((unsigned)hh[g*8+3] << 16);
        ph.z = hh[g*8+4] | ((unsigned)hh[g*8+5] << 16);
        ph.w = hh[g*8+6] | ((unsigned)hh[g*8+7] << 16);
        pl.x = ll[g*8+0] | ((unsigned)ll[g*8+1] << 16);
        pl.y = ll[g*8+2] | ((unsigned)ll[g*8+3] << 16);
        pl.z = ll[g*8+4] | ((unsigned)ll[g*8+5] << 16);
        pl.w = ll[g*8+6] | ((unsigned)ll[g*8+7] << 16);
        *(uint4*)&Ah[o + g*8] = ph;
        *(uint4*)&Al[o + g*8] = pl;
      }
      size_t gb = (size_t)(n0 + srow) * EMB + k0 + shalf;
      uint4 bh0 = *(const uint4*)(Wh + gb), bh1 = *(const uint4*)(Wh + gb + 8);
      uint4 bl0 = *(const uint4*)(Wl + gb), bl1 = *(const uint4*)(Wl + gb + 8);
      *(uint4*)&Bh[o] = bh0; *(uint4*)&Bh[o + 8] = bh1;
      *(uint4*)&Bl[o] = bl0; *(uint4*)&Bl[o + 8] = bl1;
    }
    __syncthreads();
    frag8 fbh[4], fbl[4];
#pragma unroll
    for (int nt = 0; nt < 4; ++nt) {
      int ob = (wn + nt * 16 + r16) * 40 + quad * 8;
      fbh[nt] = *(const frag8*)&Bh[ob];
      fbl[nt] = *(const frag8*)&Bl[ob];
    }
#pragma unroll
    for (int mt = 0; mt < 4; ++mt) {
      int oa = (wm + mt * 16 + r16) * 40 + quad * 8;
      frag8 fah = *(const frag8*)&Ah[oa];
      frag8 fal = *(const frag8*)&Al[oa];
#pragma unroll
      for (int nt = 0; nt < 4; ++nt) {
        acc[mt][nt] = __builtin_amdgcn_mfma_f32_16x16x32_bf16(fah, fbh[nt], acc[mt][nt], 0, 0, 0);
        acc[mt][nt] = __builtin_amdgcn_mfma_f32_16x16x32_bf16(fah, fbl[nt], acc[mt][nt], 0, 0, 0);
        acc[mt][nt] = __builtin_amdgcn_mfma_f32_16x16x32_bf16(fal, fbh[nt], acc[mt][nt], 0, 0, 0);
      }
    }
  }
#pragma unroll
  for (int nt = 0; nt < 4; ++nt) {
    int cg = n0 + wn + nt * 16 + r16;
    float bvv = bias[cg];
#pragma unroll
    for (int mt = 0; mt < 4; ++mt) {
      int rb = m0 + wm + mt * 16 + quad * 4;
#pragma unroll
      for (int r = 0; r < 4; ++r)
        out[(size_t)(rb + r) * EMB + cg] = acc[mt][nt][r] + bvv;
    }
  }
}

// ---------------------------------------------------------------------------
// Top-k per row (radix-256), with margin flagging into per-batch lists.
// ---------------------------------------------------------------------------
__global__ __launch_bounds__(256) void topk_idx(
    const float* __restrict__ scores, u16* __restrict__ idxl,
    int* __restrict__ flagcnt, int* __restrict__ flaglist)
{
  __shared__ int hist[4][256];
  __shared__ int sel[2];
  __shared__ int wsum[4];
  __shared__ unsigned wmax[4];
  const int r = blockIdx.x;
  const int tid = threadIdx.x;
  const int lane = tid & 63, wid = tid >> 6;
  const float* row = scores + (size_t)r * SEQ;
  unsigned key[8];
  {
    float4 f0 = *(const float4*)(row + tid * 8);
    float4 f1 = *(const float4*)(row + tid * 8 + 4);
    key[0]=f2ord(f0.x); key[1]=f2ord(f0.y); key[2]=f2ord(f0.z); key[3]=f2ord(f0.w);
    key[4]=f2ord(f1.x); key[5]=f2ord(f1.y); key[6]=f2ord(f1.z); key[7]=f2ord(f1.w);
  }
  unsigned V; int MEQ;
  tk_radix(key, tid, hist, sel, V, MEQ);

  {
    int ceq = 0; unsigned mk = 0;
#pragma unroll
    for (int j = 0; j < 8; ++j) {
      ceq += (key[j] == V) ? 1 : 0;
      if (key[j] < V && key[j] > mk) mk = key[j];
    }
#pragma unroll
    for (int off = 32; off > 0; off >>= 1) {
      ceq += __shfl_down(ceq, off, 64);
      unsigned o = (unsigned)__shfl_down((int)mk, off, 64);
      if (o > mk) mk = o;
    }
    if (lane == 0) { wsum[wid] = ceq; wmax[wid] = mk; }
    __syncthreads();
    if (tid == 0) {
      int EQ = wsum[0] + wsum[1] + wsum[2] + wsum[3];
      unsigned m2 = wmax[0];
      for (int w = 1; w < 4; ++w) if (wmax[w] > m2) m2 = wmax[w];
      bool flag = (EQ > MEQ) || !(ord2f(V) - ord2f(m2) >= MBOUND);
      if (flag) {
        int bb = r >> 11;
        int p = atomicAdd(&flagcnt[bb], 1);
        flaglist[bb * SEQ + p] = r & (SEQ - 1);
      }
    }
    __syncthreads();
  }

  tk_write(key, V, MEQ, tid, idxl + (size_t)r * IDXP, wsum);
}

// ---------------------------------------------------------------------------
// Fixup A: exact fp32 scores for flagged rows (gathered-A 64x64 GEMM).
// ---------------------------------------------------------------------------
__global__ __launch_bounds__(256) void fixup_gemm(
    const float* __restrict__ x, const int* __restrict__ flagcnt,
    const int* __restrict__ flaglist, float* __restrict__ attn)
{
  const int b = blockIdx.z;
  const int n = flagcnt[b];
  const int g0 = blockIdx.y * 64;
  if (g0 >= n) return;
  __shared__ float As[16][68];
  __shared__ float Bs[16][68];
  __shared__ int rowsh[64];
  const int tid = threadIdx.x;
  const int n0 = blockIdx.x * 64;
  if (tid < 64) {
    int gi = g0 + tid;
    rowsh[tid] = (gi < n) ? flaglist[b * SEQ + gi] : -1;
  }
  __syncthreads();
  const float* xb = x + (size_t)b * SEQ * EMB;
  const int lm = tid >> 2;
  const int lk = (tid & 3) << 2;
  const int mt = tid >> 4;
  const int nt = tid & 15;
  const int arow = rowsh[lm];
  const int arowL = (arow < 0) ? 0 : arow;
  float acc[4][4] = {{0.f}};
  for (int k0 = 0; k0 < EMB; k0 += 16) {
    float4 av = *(const float4*)(xb + (size_t)arowL * EMB + k0 + lk);
    float4 bv = *(const float4*)(xb + (size_t)(n0 + lm) * EMB + k0 + lk);
    __syncthreads();
    As[lk+0][lm] = av.x; As[lk+1][lm] = av.y; As[lk+2][lm] = av.z; As[lk+3][lm] = av.w;
    Bs[lk+0][lm] = bv.x; Bs[lk+1][lm] = bv.y; Bs[lk+2][lm] = bv.z; Bs[lk+3][lm] = bv.w;
    __syncthreads();
#pragma unroll
    for (int kk = 0; kk < 16; ++kk) {
      float4 a4 = *(const float4*)&As[kk][mt << 2];
      float4 b4 = *(const float4*)&Bs[kk][nt << 2];
      acc[0][0] += a4.x*b4.x; acc[0][1] += a4.x*b4.y; acc[0][2] += a4.x*b4.z; acc[0][3] += a4.x*b4.w;
      acc[1][0] += a4.y*b4.x; acc[1][1] += a4.y*b4.y; acc[1][2] += a4.y*b4.z; acc[1][3] += a4.y*b4.w;
      acc[2][0] += a4.z*b4.x; acc[2][1] += a4.z*b4.y; acc[2][2] += a4.z*b4.z; acc[2][3] += a4.z*b4.w;
      acc[3][0] += a4.w*b4.x; acc[3][1] += a4.w*b4.y; acc[3][2] += a4.w*b4.z; acc[3][3] += a4.w*b4.w;
    }
  }
  float* attnB = attn + (size_t)b * SEQ * SEQ;
#pragma unroll
  for (int r = 0; r < 4; ++r) {
    int rr = rowsh[(mt << 2) + r];
    if (rr >= 0) {
      float4 o;
      o.x = acc[r][0] * 0.0625f; o.y = acc[r][1] * 0.0625f;
      o.z = acc[r][2] * 0.0625f; o.w = acc[r][3] * 0.0625f;
      *(float4*)(attnB + (size_t)rr * SEQ + n0 + (nt << 2)) = o;
    }
  }
}

// ---------------------------------------------------------------------------
// Fixup B: redo top-k (radix) on the now-exact flagged rows.
// ---------------------------------------------------------------------------
__global__ __launch_bounds__(256) void topk_fixup(
    const float* __restrict__ attn, const int* __restrict__ flagcnt,
    const int* __restrict__ flaglist, u16* __restrict__ idxl)
{
  const int b = blockIdx.y;
  if ((int)blockIdx.x >= flagcnt[b]) return;
  const int r = b * SEQ + flaglist[b * SEQ + blockIdx.x];
  __shared__ int hist[4][256];
  __shared__ int sel[2];
  __shared__ int wsum[4];
  const int tid = threadIdx.x;
  const float* row = attn + (size_t)r * SEQ;
  unsigned key[8];
  {
    float4 f0 = *(const float4*)(row + tid * 8);
    float4 f1 = *(const float4*)(row + tid * 8 + 4);
    key[0]=f2ord(f0.x); key[1]=f2ord(f0.y); key[2]=f2ord(f0.z); key[3]=f2ord(f0.w);
    key[4]=f2ord(f1.x); key[5]=f2ord(f1.y); key[6]=f2ord(f1.z); key[7]=f2ord(f1.w);
  }
  unsigned V; int MEQ;
  tk_radix(key, tid, hist, sel, V, MEQ);
  tk_write(key, V, MEQ, tid, idxl + (size_t)r * IDXP, wsum);
}

// ---------------------------------------------------------------------------
// Sparse attention v8: fused single pass (v7 algorithm — CORRECT per R3 run,
// absmax identical to v6) + register discipline. R3's failure mode was
// occupancy: unroll-4 held 4x(K+V) payloads live -> 84 VGPR -> 4 waves/SIMD.
// Fixes: __launch_bounds__(256,8) caps alloc at 64 VGPR (8 waves/SIMD);
// unroll 2; V gather issued AFTER the dot->shfl->exp chain so vv's live
// range doesn't straddle it (TLP hides the exposed V latency).
// ---------------------------------------------------------------------------
__global__ __launch_bounds__(256, 8) void sparse_attn(
    const u16* __restrict__ qf, const u16* __restrict__ kf,
    const u16* __restrict__ vf, const u16* __restrict__ idxl,
    float* __restrict__ attn, float* __restrict__ ctxb)
{
  const int lin = blockIdx.x;
  const int b = lin & 3;                                  // XCD-stable batch
  const int q = (lin >> 3) + (((lin >> 2) & 1) << 10);
  const int tid = threadIdx.x;
  const int wv = tid >> 6, ln = tid & 63;
  const int half = ln >> 5, sl = ln & 31;
  const int h = sl >> 2, d0 = sl * 8;
  const int lb = sl * 16;
  __shared__ int   ish[IDXP];
  __shared__ int   koff[IDXP];
  __shared__ float psh[IDXP * 9 + 4];   // [j][h], stride 9 (raw exp, unnormalized)
  __shared__ float idsh[NH];
  __shared__ float rcsh[2112];          // union: rsh[2048] | csh[8][264]
#define CSH(i, j) rcsh[(i) * 264 + (j)]

  const int row = b * SEQ + q;
  if (tid < KTOP) {
    int idx = (int)idxl[(size_t)row * IDXP + tid];
    ish[tid] = idx;
    koff[tid] = idx << 9;
  } else if (tid < IDXP) {
    ish[tid] = 0; koff[tid] = 0;
  }

  float4 z4 = make_float4(0.f, 0.f, 0.f, 0.f);
  *(float4*)&rcsh[tid * 4]        = z4;
  *(float4*)&rcsh[1024 + tid * 4] = z4;

  U4 qv;
  qv.u = *(const uint4*)((const char*)(qf + (size_t)row * EMB) + lb);

  __syncthreads();

  const float scale = 0.17677669529663687f;  // 1/sqrt(32)
  const char* kbC = (const char*)(kf + (size_t)(b * SEQ) * EMB);
  const char* vbC = (const char*)(vf + (size_t)(b * SEQ) * EMB);
  const int jb = wv * KPW;
  float a8[8] = {0.f,0.f,0.f,0.f,0.f,0.f,0.f,0.f};
#pragma unroll 2
  for (int t = 0; t < KPW; t += 2) {
    const int j = jb + t + half;
    const int off = koff[j] + lb;
    U4 kv;
    kv.u = *(const uint4*)(kbC + off);
    float s = FDOT2(qv.h[0], kv.h[0],
              FDOT2(qv.h[1], kv.h[1],
              FDOT2(qv.h[2], kv.h[2],
              FDOT2(qv.h[3], kv.h[3], 0.f))));
    s += __shfl_xor(s, 1, 64);
    s += __shfl_xor(s, 2, 64);
    float p = (j < KTOP) ? __expf(s * scale) : 0.f;
    if ((sl & 3) == 0 && j < KTOP) psh[j * 9 + h] = p;
    U4 vv;
    vv.u = *(const uint4*)(vbC + off);
    a8[0] += p * (float)vv.h[0][0]; a8[1] += p * (float)vv.h[0][1];
    a8[2] += p * (float)vv.h[1][0]; a8[3] += p * (float)vv.h[1][1];
    a8[4] += p * (float)vv.h[2][0]; a8[5] += p * (float)vv.h[2][1];
    a8[6] += p * (float)vv.h[3][0]; a8[7] += p * (float)vv.h[3][1];
  }
  __syncthreads();

  // per-head denominators
  {
    int h2 = tid >> 5, l = tid & 31;
    float sden = 0.f;
    for (int j = l; j < KTOP; j += 32) sden += psh[j * 9 + h2];
#pragma unroll
    for (int off = 16; off > 0; off >>= 1) sden += __shfl_down(sden, off, 32);
    if (l == 0) idsh[h2] = 1.0f / sden;
  }
  __syncthreads();

  // head-averaged normalized probs -> scatter into the dense row
  if (tid < KTOP) {
    float ps = 0.f;
#pragma unroll
    for (int hh = 0; hh < 8; ++hh) ps += psh[tid * 9 + hh] * idsh[hh];
    rcsh[ish[tid]] = ps * 0.125f;
  }
  __syncthreads();

  // stream dense row out (full-line, conflict-free)
  {
    float* arow = attn + (size_t)row * SEQ;
    *(float4*)(arow + tid * 4)        = *(const float4*)&rcsh[tid * 4];
    *(float4*)(arow + 1024 + tid * 4) = *(const float4*)&rcsh[1024 + tid * 4];
  }
  __syncthreads();   // rsh dead; csh may now overwrite the region

  // normalize context partials (late 1/den) and reduce across wave-halves
  {
    const float sc = idsh[h];
    const int pi = wv * 2 + half;
    *(float4*)&CSH(pi, d0)     = make_float4(a8[0]*sc, a8[1]*sc, a8[2]*sc, a8[3]*sc);
    *(float4*)&CSH(pi, d0 + 4) = make_float4(a8[4]*sc, a8[5]*sc, a8[6]*sc, a8[7]*sc);
  }
  __syncthreads();
  if (tid < 64) {
    float4 o = z4;
#pragma unroll
    for (int g = 0; g < 8; ++g) {
      float4 v = *(const float4*)&CSH(g, tid * 4);
      o.x += v.x; o.y += v.y; o.z += v.z; o.w += v.w;
    }
    *(float4*)(ctxb + (size_t)row * EMB + tid * 4) = o;
  }
#undef CSH
}

// ---------------------------------------------------------------------------
extern "C" void kernel_launch(void* const* d_in, const int* in_sizes, int n_in,
                              void* d_out, int out_size, void* d_ws, size_t ws_size,
                              hipStream_t stream)
{
  const float* x  = (const float*)d_in[0];
  const float* Wq = (const float*)d_in[1];
  const float* bq = (const float*)d_in[2];
  const float* Wk = (const float*)d_in[3];
  const float* bk = (const float*)d_in[4];
  const float* Wv = (const float*)d_in[5];
  const float* bv = (const float*)d_in[6];
  const float* Wo = (const float*)d_in[7];
  const float* bo = (const float*)d_in[8];

  float* out  = (float*)d_out;
  float* attn = out + (size_t)NB * SEQ * EMB;   // [B,S,S] region of d_out

  const size_t NSE = (size_t)NB * SEQ * EMB;    // 2097152
  u16* xh  = (u16*)d_ws;            // bf16 hi of x
  u16* xl  = xh + NSE;              // bf16 lo
  u16* qf  = xl + NSE;              // f16 Q
  u16* kf  = qf + NSE;              // f16 K
  u16* vf  = kf + NSE;              // f16 V
  u16* wpk = vf + NSE;              // 4 x (hi,lo) 256x256 bf16
  float* ctxb = (float*)(wpk + 4 * 2 * 65536);
  u16* idxl = (u16*)(ctxb + NSE);
  int* flagcnt  = (int*)(idxl + (size_t)NB * SEQ * IDXP);
  int* flaglist = flagcnt + NB;

  const dim3 blk(256);

  // hi/lo splits of x + weights (one launch); flag counters reset
  pack_all<<<dim3(1152), blk, 0, stream>>>(x, Wq, Wk, Wv, Wo, xh, xl, wpk, flagcnt);

  // symmetric scores (544 upper-triangle blocks) + QKV (384) in one launch
  fused_gemms<<<dim3(928), blk, 0, stream>>>(xh, xl, wpk, bq, bk, bv,
                                             qf, kf, vf, attn);

  // radix top-k with margin flagging; exact fp32 fixup of low-margin rows
  topk_idx<<<dim3(NB * SEQ), blk, 0, stream>>>(attn, idxl, flagcnt, flaglist);
  fixup_gemm<<<dim3(32, 32, NB), blk, 0, stream>>>(x, flagcnt, flaglist, attn);
  topk_fixup<<<dim3(SEQ, NB), blk, 0, stream>>>(attn, flagcnt, flaglist, idxl);

  // fused single-pass sparse attention (v8: 64-VGPR cap, unroll 2)
  sparse_attn<<<dim3(SEQ * NB), blk, 0, stream>>>(qf, kf, vf, idxl, attn, ctxb);

  // out = ctx @ Wo^T + bo (in-kernel hi/lo split of ctx)
  out_mfma<<<dim3(64, 2), blk, 0, stream>>>(ctxb, wpk, bo, out);
}

// Round 6
// 313.845 us; speedup vs baseline: 1.1159x; 1.0182x over previous
//
#include <hip/hip_runtime.h>

#define SEQ  2048
#define EMB  256
#define NH   8
#define HD   32
#define NB   4
#define KTOP 204
#define IDXP 208
#define KPW  52       // keys per wave (4*52 = 208, padded)
#define MBOUND 4e-4f  // top-k margin for fp32 re-verify

typedef unsigned long long ull;
typedef unsigned short u16;

using frag8  = __attribute__((ext_vector_type(8))) short;  // 8 bf16
using f32x4v = __attribute__((ext_vector_type(4))) float;
typedef _Float16 f16;
typedef _Float16 f16x2 __attribute__((ext_vector_type(2)));

union U4 { uint4 u; f16x2 h[4]; };
union HU { f16 h; u16 u; };

#if defined(__has_builtin)
#if __has_builtin(__builtin_amdgcn_fdot2)
#define FDOT2(a,b,c) __builtin_amdgcn_fdot2(a, b, c, false)
#endif
#endif
#ifndef FDOT2
__device__ __forceinline__ float fdot2_sw(f16x2 a, f16x2 b, float c) {
  return c + (float)a[0]*(float)b[0] + (float)a[1]*(float)b[1];
}
#define FDOT2(a,b,c) fdot2_sw(a,b,c)
#endif

__device__ __forceinline__ unsigned f2ord(float f) {
  unsigned u = __float_as_uint(f);
  return (u & 0x80000000u) ? ~u : (u | 0x80000000u);
}
__device__ __forceinline__ float ord2f(unsigned o) {
  unsigned u = (o & 0x80000000u) ? (o ^ 0x80000000u) : ~o;
  return __uint_as_float(u);
}
__device__ __forceinline__ u16 f2bf(float f) {
  unsigned u = __float_as_uint(f);
  u += 0x7FFF + ((u >> 16) & 1);     // RTNE
  return (u16)(u >> 16);
}
__device__ __forceinline__ float bf2f(u16 h) {
  return __uint_as_float((unsigned)h << 16);
}

// ---------------------------------------------------------------------------
// Async staging of one 128x32 bf16 tile via global_load_lds (width 16).
// LDS layout is LINEAR in slot S (16B each); the fragment-layout permutation
// is folded into the per-lane GLOBAL source address (swizzle-both-sides):
//   slot S holds (row = S>>2, quad = (S&3) ^ ((S>>3)&3)).
// Fragment read address: row*32 + (quad ^ ((row>>1)&3))*8  (u16 units) —
// a bijection onto contiguous 1KB per wave-read -> conflict-free.
// ---------------------------------------------------------------------------
__device__ __forceinline__ void stage128x32(
    const u16* __restrict__ src, int row0, int k0, u16* lds, int wv, int ln)
{
#pragma unroll
  for (int i = 0; i < 2; ++i) {
    const int S = wv * 128 + i * 64 + ln;
    const int row = S >> 2;
    const int q = (S & 3) ^ ((S >> 3) & 3);
    const u16* g = src + (size_t)(row0 + row) * EMB + k0 + q * 8;
    __builtin_amdgcn_global_load_lds(
        (const __attribute__((address_space(1))) unsigned*)g,
        (__attribute__((address_space(3))) unsigned*)(lds + (size_t)(S - ln) * 8),
        16, 0, 0);
  }
}

// ---------------------------------------------------------------------------
// Radix-256 top-k (4 byte passes, per-wave histograms, wave-0 suffix scan).
// ---------------------------------------------------------------------------
__device__ __forceinline__ void tk_radix(
    const unsigned key[8], int tid, int (*hist)[256], int* sel,
    unsigned& V, int& MEQ)
{
  const int lane = tid & 63, wid = tid >> 6;
  unsigned prefix = 0;
  int k = KTOP;
#pragma unroll
  for (int p = 0; p < 4; ++p) {
    const int shift = 24 - 8 * p;
    hist[0][tid] = 0; hist[1][tid] = 0; hist[2][tid] = 0; hist[3][tid] = 0;
    __syncthreads();
#pragma unroll
    for (int j = 0; j < 8; ++j) {
      unsigned kj = key[j];
      bool ok = (p == 0) || ((kj >> (shift + 8)) == prefix);
      if (ok) atomicAdd(&hist[wid][(kj >> shift) & 255], 1);
    }
    __syncthreads();
    {
      int c = hist[0][tid] + hist[1][tid] + hist[2][tid] + hist[3][tid];
      hist[0][tid] = c;
    }
    __syncthreads();
    if (wid == 0) {
      int m0 = hist[0][lane * 4 + 0], m1 = hist[0][lane * 4 + 1];
      int m2 = hist[0][lane * 4 + 2], m3 = hist[0][lane * 4 + 3];
      int sl = m0 + m1 + m2 + m3;
      int suf = sl;
#pragma unroll
      for (int off = 1; off < 64; off <<= 1) {
        int y = __shfl_down(suf, off, 64);
        if (lane + off < 64) suf += y;
      }
      int above = suf - sl;
      if (above < k && k <= suf) {
        int bin, nk;
        if (k <= above + m3)                { bin = lane*4+3; nk = k - above; }
        else if (k <= above + m3 + m2)      { bin = lane*4+2; nk = k - above - m3; }
        else if (k <= above + m3 + m2 + m1) { bin = lane*4+1; nk = k - above - m3 - m2; }
        else                                { bin = lane*4+0; nk = k - above - m3 - m2 - m1; }
        sel[0] = bin; sel[1] = nk;
      }
    }
    __syncthreads();
    prefix = (prefix << 8) | (unsigned)sel[0];
    k = sel[1];
    __syncthreads();
  }
  V = prefix;
  MEQ = k;
}

__device__ __forceinline__ int tk_scan_excl(int v, int tid, int* wsum) {
  const int lane = tid & 63, wid = tid >> 6;
  int x = v;
#pragma unroll
  for (int off = 1; off < 64; off <<= 1) {
    int y = __shfl_up(x, off, 64);
    if (lane >= off) x += y;
  }
  if (lane == 63) wsum[wid] = x;
  __syncthreads();
  int base = 0;
  for (int w = 0; w < wid; ++w) base += wsum[w];
  return base + x - v;
}

__device__ __forceinline__ void tk_write(const unsigned key[8], unsigned V, int MEQ,
                                         int tid, u16* orow, int* wsum) {
  int ceq = 0;
#pragma unroll
  for (int j = 0; j < 8; ++j) ceq += (key[j] == V) ? 1 : 0;
  int run = tk_scan_excl(ceq, tid, wsum);
  unsigned bits = 0;
#pragma unroll
  for (int j = 0; j < 8; ++j) {
    bool e = (key[j] == V);
    bool s = (key[j] > V) || (e && (run < MEQ));
    if (e) run++;
    if (s) bits |= (1u << j);
  }
  int csel = __popc(bits);
  __syncthreads();
  int base = tk_scan_excl(csel, tid, wsum);
#pragma unroll
  for (int j = 0; j < 8; ++j)
    if ((bits >> j) & 1u) orow[base++] = (u16)(tid * 8 + j);
}

// ---------------------------------------------------------------------------
// pack_all: bf16 hi/lo split of x (blocks 0..1023) and the 4 weight matrices
// (blocks 1024..1151); block 0 also zeroes the per-batch flag counters.
// ---------------------------------------------------------------------------
__global__ __launch_bounds__(256) void pack_all(
    const float* __restrict__ x,
    const float* __restrict__ W0, const float* __restrict__ W1,
    const float* __restrict__ W2, const float* __restrict__ W3,
    u16* __restrict__ xh, u16* __restrict__ xl, u16* __restrict__ wpk,
    int* __restrict__ flagcnt)
{
  const int lin = blockIdx.x;
  if (lin == 0 && threadIdx.x < NB) flagcnt[threadIdx.x] = 0;
  const float* src; u16 *dh, *dl; int i;
  if (lin < 1024) {
    src = x;
    i = (lin * 256 + threadIdx.x) * 8;
    dh = xh; dl = xl;
  } else {
    int j = lin - 1024;             // 0..127
    int m = j >> 5, bx = j & 31;
    src = (m == 0) ? W0 : (m == 1) ? W1 : (m == 2) ? W2 : W3;
    i = (bx * 256 + threadIdx.x) * 8;
    dh = wpk + (size_t)m * 2 * 65536;
    dl = dh + 65536;
  }
  float4 a = *(const float4*)(src + i);
  float4 b = *(const float4*)(src + i + 4);
  float v[8] = {a.x,a.y,a.z,a.w,b.x,b.y,b.z,b.w};
  u16 h[8], l[8];
#pragma unroll
  for (int j = 0; j < 8; ++j) {
    h[j] = f2bf(v[j]);
    l[j] = f2bf(v[j] - bf2f(h[j]));
  }
  uint4 ph, pl;
  ph.x = h[0] | ((unsigned)h[1] << 16); ph.y = h[2] | ((unsigned)h[3] << 16);
  ph.z = h[4] | ((unsigned)h[5] << 16); ph.w = h[6] | ((unsigned)h[7] << 16);
  pl.x = l[0] | ((unsigned)l[1] << 16); pl.y = l[2] | ((unsigned)l[3] << 16);
  pl.z = l[4] | ((unsigned)l[5] << 16); pl.w = l[6] | ((unsigned)l[7] << 16);
  *(uint4*)(dh + i) = ph;
  *(uint4*)(dl + i) = pl;
}

// ---------------------------------------------------------------------------
// fused_gemms: scores (SYMMETRIC — upper-triangle blocks only, mirror written
// from registers; blocks 0..543) + QKV projections (blocks 544..927).
// v9: staging via global_load_lds width-16 into linear LDS with the fragment
// permutation pre-applied to the global source address (no reg round-trip,
// no LDS padding; conflict-free swizzled reads). MFMA sequence unchanged.
// Scores use 3-term hi/lo MFMA (lo*lo dropped; error ~3e-6 << MBOUND).
// ---------------------------------------------------------------------------
__global__ __launch_bounds__(256) void fused_gemms(
    const u16* __restrict__ xh, const u16* __restrict__ xl,
    const u16* __restrict__ wpk,
    const float* __restrict__ bq, const float* __restrict__ bk,
    const float* __restrict__ bv,
    u16* __restrict__ qo, u16* __restrict__ ko, u16* __restrict__ vo,
    float* __restrict__ attnC)
{
  __shared__ u16 Ah[128 * 32], Al[128 * 32], Bh[128 * 32], Bl[128 * 32];
  const int lin = blockIdx.x;
  const int tid = threadIdx.x;
  const int wv = tid >> 6, ln = tid & 63;
  const int quad = ln >> 4, r16 = ln & 15;
  const int perm = quad ^ ((r16 >> 1) & 3);     // read-side swizzle (matches stage)
  const int wm = (wv & 1) * 64, wn = (wv >> 1) * 64;

  f32x4v acc[4][4];
#pragma unroll
  for (int i = 0; i < 4; ++i)
#pragma unroll
    for (int j = 0; j < 4; ++j) acc[i][j] = (f32x4v){0.f, 0.f, 0.f, 0.f};

  if (lin < 544) {
    // ----- scores path (symmetric, bi <= bj) -----
    const int b = lin / 136;
    int p = lin - b * 136;
    int bi = 0;
    while (p >= 16 - bi) { p -= 16 - bi; ++bi; }
    const int bj = bi + p;
    const int m0 = bi * 128, n0 = bj * 128;
    const u16* xhB = xh + (size_t)b * SEQ * EMB;
    const u16* xlB = xl + (size_t)b * SEQ * EMB;
    float* Cb = attnC + (size_t)b * SEQ * SEQ;
    for (int k0 = 0; k0 < EMB; k0 += 32) {
      __syncthreads();
      stage128x32(xhB, m0, k0, Ah, wv, ln);
      stage128x32(xlB, m0, k0, Al, wv, ln);
      stage128x32(xhB, n0, k0, Bh, wv, ln);
      stage128x32(xlB, n0, k0, Bl, wv, ln);
      __syncthreads();
      frag8 fbh[4], fbl[4];
#pragma unroll
      for (int nt = 0; nt < 4; ++nt) {
        int ob = ((wn + nt * 16 + r16) << 5) + (perm << 3);
        fbh[nt] = *(const frag8*)&Bh[ob];
        fbl[nt] = *(const frag8*)&Bl[ob];
      }
#pragma unroll
      for (int mt = 0; mt < 4; ++mt) {
        int oa = ((wm + mt * 16 + r16) << 5) + (perm << 3);
        frag8 fah = *(const frag8*)&Ah[oa];
        frag8 fal = *(const frag8*)&Al[oa];
#pragma unroll
        for (int nt = 0; nt < 4; ++nt) {
          acc[mt][nt] = __builtin_amdgcn_mfma_f32_16x16x32_bf16(fah, fbh[nt], acc[mt][nt], 0, 0, 0);
          acc[mt][nt] = __builtin_amdgcn_mfma_f32_16x16x32_bf16(fah, fbl[nt], acc[mt][nt], 0, 0, 0);
          acc[mt][nt] = __builtin_amdgcn_mfma_f32_16x16x32_bf16(fal, fbh[nt], acc[mt][nt], 0, 0, 0);
        }
      }
    }
    // normal write (upper block)
#pragma unroll
    for (int mt = 0; mt < 4; ++mt)
#pragma unroll
      for (int nt = 0; nt < 4; ++nt) {
        int cg = n0 + wn + nt * 16 + r16;
        int rb = m0 + wm + mt * 16 + quad * 4;
#pragma unroll
        for (int r = 0; r < 4; ++r)
          Cb[(size_t)(rb + r) * SEQ + cg] = acc[mt][nt][r] * 0.0625f;
      }
    // mirror write (lower block): element (rb+r, cg) -> (cg, rb+r).
    if (bi != bj) {
#pragma unroll
      for (int mt = 0; mt < 4; ++mt)
#pragma unroll
        for (int nt = 0; nt < 4; ++nt) {
          int cg = n0 + wn + nt * 16 + r16;
          int rb = m0 + wm + mt * 16 + quad * 4;
          float4 o;
          o.x = acc[mt][nt][0] * 0.0625f;
          o.y = acc[mt][nt][1] * 0.0625f;
          o.z = acc[mt][nt][2] * 0.0625f;
          o.w = acc[mt][nt][3] * 0.0625f;
          *(float4*)&Cb[(size_t)cg * SEQ + rb] = o;
        }
    }
  } else {
    // ----- qkv path -----
    const int j = lin - 544;
    const int m0 = (j & 63) * 128, n0 = ((j >> 6) & 1) * 128;
    const int z = j >> 7;
    const u16* Wh = wpk + (size_t)z * 2 * 65536;
    const u16* Wl = Wh + 65536;
    const float* bias = (z == 0) ? bq : (z == 1) ? bk : bv;
    u16* out = (z == 0) ? qo : (z == 1) ? ko : vo;
    for (int k0 = 0; k0 < EMB; k0 += 32) {
      __syncthreads();
      stage128x32(xh, m0, k0, Ah, wv, ln);
      stage128x32(xl, m0, k0, Al, wv, ln);
      stage128x32(Wh, n0, k0, Bh, wv, ln);
      stage128x32(Wl, n0, k0, Bl, wv, ln);
      __syncthreads();
      frag8 fbh[4], fbl[4];
#pragma unroll
      for (int nt = 0; nt < 4; ++nt) {
        int ob = ((wn + nt * 16 + r16) << 5) + (perm << 3);
        fbh[nt] = *(const frag8*)&Bh[ob];
        fbl[nt] = *(const frag8*)&Bl[ob];
      }
#pragma unroll
      for (int mt = 0; mt < 4; ++mt) {
        int oa = ((wm + mt * 16 + r16) << 5) + (perm << 3);
        frag8 fah = *(const frag8*)&Ah[oa];
        frag8 fal = *(const frag8*)&Al[oa];
#pragma unroll
        for (int nt = 0; nt < 4; ++nt) {
          acc[mt][nt] = __builtin_amdgcn_mfma_f32_16x16x32_bf16(fah, fbh[nt], acc[mt][nt], 0, 0, 0);
          acc[mt][nt] = __builtin_amdgcn_mfma_f32_16x16x32_bf16(fah, fbl[nt], acc[mt][nt], 0, 0, 0);
          acc[mt][nt] = __builtin_amdgcn_mfma_f32_16x16x32_bf16(fal, fbh[nt], acc[mt][nt], 0, 0, 0);
        }
      }
    }
#pragma unroll
    for (int nt = 0; nt < 4; ++nt) {
      int cg = n0 + wn + nt * 16 + r16;
      float bvv = bias[cg];
#pragma unroll
      for (int mt = 0; mt < 4; ++mt) {
        int rb = m0 + wm + mt * 16 + quad * 4;
#pragma unroll
        for (int r = 0; r < 4; ++r) {
          HU hu; hu.h = (f16)(acc[mt][nt][r] + bvv);
          out[(size_t)(rb + r) * EMB + cg] = hu.u;
        }
      }
    }
  }
}

// ---------------------------------------------------------------------------
// Out projection: stages fp32 ctx, splits hi/lo in-kernel (3-term MFMA).
// (unchanged — in-kernel split needs the reg round-trip anyway)
// ---------------------------------------------------------------------------
__global__ __launch_bounds__(256) void out_mfma(
    const float* __restrict__ ctx, const u16* __restrict__ wpk,
    const float* __restrict__ bias, float* __restrict__ out)
{
  const u16* Wh = wpk + (size_t)3 * 2 * 65536;
  const u16* Wl = Wh + 65536;
  __shared__ u16 Ah[128 * 40], Al[128 * 40], Bh[128 * 40], Bl[128 * 40];
  const int tid = threadIdx.x;
  const int m0 = blockIdx.x * 128, n0 = blockIdx.y * 128;
  const int wv = tid >> 6, ln = tid & 63;
  const int quad = ln >> 4, r16 = ln & 15;
  const int wm = (wv & 1) * 64, wn = (wv >> 1) * 64;
  const int srow = tid >> 1, shalf = (tid & 1) * 16;

  f32x4v acc[4][4];
#pragma unroll
  for (int i = 0; i < 4; ++i)
#pragma unroll
    for (int j = 0; j < 4; ++j) acc[i][j] = (f32x4v){0.f, 0.f, 0.f, 0.f};

  for (int k0 = 0; k0 < EMB; k0 += 32) {
    __syncthreads();
    {
      size_t ga = (size_t)(m0 + srow) * EMB + k0 + shalf;
      float4 c0 = *(const float4*)(ctx + ga);
      float4 c1 = *(const float4*)(ctx + ga + 4);
      float4 c2 = *(const float4*)(ctx + ga + 8);
      float4 c3 = *(const float4*)(ctx + ga + 12);
      float v[16] = {c0.x,c0.y,c0.z,c0.w, c1.x,c1.y,c1.z,c1.w,
                     c2.x,c2.y,c2.z,c2.w, c3.x,c3.y,c3.z,c3.w};
      u16 hh[16], ll[16];
#pragma unroll
      for (int jj = 0; jj < 16; ++jj) {
        hh[jj] = f2bf(v[jj]);
        ll[jj] = f2bf(v[jj] - bf2f(hh[jj]));
      }
      int o = srow * 40 + shalf;
#pragma unroll
      for (int g = 0; g < 2; ++g) {
        uint4 ph, pl;
        ph.x = hh[g*8+0] | ((unsigned)hh[g*8+1] << 16);
        ph.y = hh[g*8+2] | ((unsigned)hh[g*8+3] << 16);
        ph.z = hh[g*8+4] | ((unsigned)hh[g*8+5] << 16);
        ph.w = hh[g*8+6] | ((unsigned)hh[g*8+7] << 16);
        pl.x = ll[g*8+0] | ((unsigned)ll[g*8+1] << 16);
        pl.y = ll[g*8+2] | ((unsigned)ll[g*8+3] << 16);
        pl.z = ll[g*8+4] | ((unsigned)ll[g*8+5] << 16);
        pl.w = ll[g*8+6] | ((unsigned)ll[g*8+7] << 16);
        *(uint4*)&Ah[o + g*8] = ph;
        *(uint4*)&Al[o + g*8] = pl;
      }
      size_t gb = (size_t)(n0 + srow) * EMB + k0 + shalf;
      uint4 bh0 = *(const uint4*)(Wh + gb), bh1 = *(const uint4*)(Wh + gb + 8);
      uint4 bl0 = *(const uint4*)(Wl + gb), bl1 = *(const uint4*)(Wl + gb + 8);
      *(uint4*)&Bh[o] = bh0; *(uint4*)&Bh[o + 8] = bh1;
      *(uint4*)&Bl[o] = bl0; *(uint4*)&Bl[o + 8] = bl1;
    }
    __syncthreads();
    frag8 fbh[4], fbl[4];
#pragma unroll
    for (int nt = 0; nt < 4; ++nt) {
      int ob = (wn + nt * 16 + r16) * 40 + quad * 8;
      fbh[nt] = *(const frag8*)&Bh[ob];
      fbl[nt] = *(const frag8*)&Bl[ob];
    }
#pragma unroll
    for (int mt = 0; mt < 4; ++mt) {
      int oa = (wm + mt * 16 + r16) * 40 + quad * 8;
      frag8 fah = *(const frag8*)&Ah[oa];
      frag8 fal = *(const frag8*)&Al[oa];
#pragma unroll
      for (int nt = 0; nt < 4; ++nt) {
        acc[mt][nt] = __builtin_amdgcn_mfma_f32_16x16x32_bf16(fah, fbh[nt], acc[mt][nt], 0, 0, 0);
        acc[mt][nt] = __builtin_amdgcn_mfma_f32_16x16x32_bf16(fah, fbl[nt], acc[mt][nt], 0, 0, 0);
        acc[mt][nt] = __builtin_amdgcn_mfma_f32_16x16x32_bf16(fal, fbh[nt], acc[mt][nt], 0, 0, 0);
      }
    }
  }
#pragma unroll
  for (int nt = 0; nt < 4; ++nt) {
    int cg = n0 + wn + nt * 16 + r16;
    float bvv = bias[cg];
#pragma unroll
    for (int mt = 0; mt < 4; ++mt) {
      int rb = m0 + wm + mt * 16 + quad * 4;
#pragma unroll
      for (int r = 0; r < 4; ++r)
        out[(size_t)(rb + r) * EMB + cg] = acc[mt][nt][r] + bvv;
    }
  }
}

// ---------------------------------------------------------------------------
// Top-k per row (radix-256), with margin flagging into per-batch lists.
// ---------------------------------------------------------------------------
__global__ __launch_bounds__(256) void topk_idx(
    const float* __restrict__ scores, u16* __restrict__ idxl,
    int* __restrict__ flagcnt, int* __restrict__ flaglist)
{
  __shared__ int hist[4][256];
  __shared__ int sel[2];
  __shared__ int wsum[4];
  __shared__ unsigned wmax[4];
  const int r = blockIdx.x;
  const int tid = threadIdx.x;
  const int lane = tid & 63, wid = tid >> 6;
  const float* row = scores + (size_t)r * SEQ;
  unsigned key[8];
  {
    float4 f0 = *(const float4*)(row + tid * 8);
    float4 f1 = *(const float4*)(row + tid * 8 + 4);
    key[0]=f2ord(f0.x); key[1]=f2ord(f0.y); key[2]=f2ord(f0.z); key[3]=f2ord(f0.w);
    key[4]=f2ord(f1.x); key[5]=f2ord(f1.y); key[6]=f2ord(f1.z); key[7]=f2ord(f1.w);
  }
  unsigned V; int MEQ;
  tk_radix(key, tid, hist, sel, V, MEQ);

  {
    int ceq = 0; unsigned mk = 0;
#pragma unroll
    for (int j = 0; j < 8; ++j) {
      ceq += (key[j] == V) ? 1 : 0;
      if (key[j] < V && key[j] > mk) mk = key[j];
    }
#pragma unroll
    for (int off = 32; off > 0; off >>= 1) {
      ceq += __shfl_down(ceq, off, 64);
      unsigned o = (unsigned)__shfl_down((int)mk, off, 64);
      if (o > mk) mk = o;
    }
    if (lane == 0) { wsum[wid] = ceq; wmax[wid] = mk; }
    __syncthreads();
    if (tid == 0) {
      int EQ = wsum[0] + wsum[1] + wsum[2] + wsum[3];
      unsigned m2 = wmax[0];
      for (int w = 1; w < 4; ++w) if (wmax[w] > m2) m2 = wmax[w];
      bool flag = (EQ > MEQ) || !(ord2f(V) - ord2f(m2) >= MBOUND);
      if (flag) {
        int bb = r >> 11;
        int p = atomicAdd(&flagcnt[bb], 1);
        flaglist[bb * SEQ + p] = r & (SEQ - 1);
      }
    }
    __syncthreads();
  }

  tk_write(key, V, MEQ, tid, idxl + (size_t)r * IDXP, wsum);
}

// ---------------------------------------------------------------------------
// Fixup A: exact fp32 scores for flagged rows (gathered-A 64x64 GEMM).
// ---------------------------------------------------------------------------
__global__ __launch_bounds__(256) void fixup_gemm(
    const float* __restrict__ x, const int* __restrict__ flagcnt,
    const int* __restrict__ flaglist, float* __restrict__ attn)
{
  const int b = blockIdx.z;
  const int n = flagcnt[b];
  const int g0 = blockIdx.y * 64;
  if (g0 >= n) return;
  __shared__ float As[16][68];
  __shared__ float Bs[16][68];
  __shared__ int rowsh[64];
  const int tid = threadIdx.x;
  const int n0 = blockIdx.x * 64;
  if (tid < 64) {
    int gi = g0 + tid;
    rowsh[tid] = (gi < n) ? flaglist[b * SEQ + gi] : -1;
  }
  __syncthreads();
  const float* xb = x + (size_t)b * SEQ * EMB;
  const int lm = tid >> 2;
  const int lk = (tid & 3) << 2;
  const int mt = tid >> 4;
  const int nt = tid & 15;
  const int arow = rowsh[lm];
  const int arowL = (arow < 0) ? 0 : arow;
  float acc[4][4] = {{0.f}};
  for (int k0 = 0; k0 < EMB; k0 += 16) {
    float4 av = *(const float4*)(xb + (size_t)arowL * EMB + k0 + lk);
    float4 bv = *(const float4*)(xb + (size_t)(n0 + lm) * EMB + k0 + lk);
    __syncthreads();
    As[lk+0][lm] = av.x; As[lk+1][lm] = av.y; As[lk+2][lm] = av.z; As[lk+3][lm] = av.w;
    Bs[lk+0][lm] = bv.x; Bs[lk+1][lm] = bv.y; Bs[lk+2][lm] = bv.z; Bs[lk+3][lm] = bv.w;
    __syncthreads();
#pragma unroll
    for (int kk = 0; kk < 16; ++kk) {
      float4 a4 = *(const float4*)&As[kk][mt << 2];
      float4 b4 = *(const float4*)&Bs[kk][nt << 2];
      acc[0][0] += a4.x*b4.x; acc[0][1] += a4.x*b4.y; acc[0][2] += a4.x*b4.z; acc[0][3] += a4.x*b4.w;
      acc[1][0] += a4.y*b4.x; acc[1][1] += a4.y*b4.y; acc[1][2] += a4.y*b4.z; acc[1][3] += a4.y*b4.w;
      acc[2][0] += a4.z*b4.x; acc[2][1] += a4.z*b4.y; acc[2][2] += a4.z*b4.z; acc[2][3] += a4.z*b4.w;
      acc[3][0] += a4.w*b4.x; acc[3][1] += a4.w*b4.y; acc[3][2] += a4.w*b4.z; acc[3][3] += a4.w*b4.w;
    }
  }
  float* attnB = attn + (size_t)b * SEQ * SEQ;
#pragma unroll
  for (int r = 0; r < 4; ++r) {
    int rr = rowsh[(mt << 2) + r];
    if (rr >= 0) {
      float4 o;
      o.x = acc[r][0] * 0.0625f; o.y = acc[r][1] * 0.0625f;
      o.z = acc[r][2] * 0.0625f; o.w = acc[r][3] * 0.0625f;
      *(float4*)(attnB + (size_t)rr * SEQ + n0 + (nt << 2)) = o;
    }
  }
}

// ---------------------------------------------------------------------------
// Fixup B: redo top-k (radix) on the now-exact flagged rows.
// ---------------------------------------------------------------------------
__global__ __launch_bounds__(256) void topk_fixup(
    const float* __restrict__ attn, const int* __restrict__ flagcnt,
    const int* __restrict__ flaglist, u16* __restrict__ idxl)
{
  const int b = blockIdx.y;
  if ((int)blockIdx.x >= flagcnt[b]) return;
  const int r = b * SEQ + flaglist[b * SEQ + blockIdx.x];
  __shared__ int hist[4][256];
  __shared__ int sel[2];
  __shared__ int wsum[4];
  const int tid = threadIdx.x;
  const float* row = attn + (size_t)r * SEQ;
  unsigned key[8];
  {
    float4 f0 = *(const float4*)(row + tid * 8);
    float4 f1 = *(const float4*)(row + tid * 8 + 4);
    key[0]=f2ord(f0.x); key[1]=f2ord(f0.y); key[2]=f2ord(f0.z); key[3]=f2ord(f0.w);
    key[4]=f2ord(f1.x); key[5]=f2ord(f1.y); key[6]=f2ord(f1.z); key[7]=f2ord(f1.w);
  }
  unsigned V; int MEQ;
  tk_radix(key, tid, hist, sel, V, MEQ);
  tk_write(key, V, MEQ, tid, idxl + (size_t)r * IDXP, wsum);
}

// ---------------------------------------------------------------------------
// Sparse attention v8 (kept): fused single pass at 24 VGPR / ~75% occupancy.
// R5 measured it at the scattered-L2 gather roofline (~20.5 TB/s of 34.5
// ceiling; gather bytes already minimal) — do not push further.
// ---------------------------------------------------------------------------
__global__ __launch_bounds__(256, 8) void sparse_attn(
    const u16* __restrict__ qf, const u16* __restrict__ kf,
    const u16* __restrict__ vf, const u16* __restrict__ idxl,
    float* __restrict__ attn, float* __restrict__ ctxb)
{
  const int lin = blockIdx.x;
  const int b = lin & 3;                                  // XCD-stable batch
  const int q = (lin >> 3) + (((lin >> 2) & 1) << 10);
  const int tid = threadIdx.x;
  const int wv = tid >> 6, ln = tid & 63;
  const int half = ln >> 5, sl = ln & 31;
  const int h = sl >> 2, d0 = sl * 8;
  const int lb = sl * 16;
  __shared__ int   ish[IDXP];
  __shared__ int   koff[IDXP];
  __shared__ float psh[IDXP * 9 + 4];   // [j][h], stride 9 (raw exp, unnormalized)
  __shared__ float idsh[NH];
  __shared__ float rcsh[2112];          // union: rsh[2048] | csh[8][264]
#define CSH(i, j) rcsh[(i) * 264 + (j)]

  const int row = b * SEQ + q;
  if (tid < KTOP) {
    int idx = (int)idxl[(size_t)row * IDXP + tid];
    ish[tid] = idx;
    koff[tid] = idx << 9;
  } else if (tid < IDXP) {
    ish[tid] = 0; koff[tid] = 0;
  }

  float4 z4 = make_float4(0.f, 0.f, 0.f, 0.f);
  *(float4*)&rcsh[tid * 4]        = z4;
  *(float4*)&rcsh[1024 + tid * 4] = z4;

  U4 qv;
  qv.u = *(const uint4*)((const char*)(qf + (size_t)row * EMB) + lb);

  __syncthreads();

  const float scale = 0.17677669529663687f;  // 1/sqrt(32)
  const char* kbC = (const char*)(kf + (size_t)(b * SEQ) * EMB);
  const char* vbC = (const char*)(vf + (size_t)(b * SEQ) * EMB);
  const int jb = wv * KPW;
  float a8[8] = {0.f,0.f,0.f,0.f,0.f,0.f,0.f,0.f};
#pragma unroll 2
  for (int t = 0; t < KPW; t += 2) {
    const int j = jb + t + half;
    const int off = koff[j] + lb;
    U4 kv;
    kv.u = *(const uint4*)(kbC + off);
    float s = FDOT2(qv.h[0], kv.h[0],
              FDOT2(qv.h[1], kv.h[1],
              FDOT2(qv.h[2], kv.h[2],
              FDOT2(qv.h[3], kv.h[3], 0.f))));
    s += __shfl_xor(s, 1, 64);
    s += __shfl_xor(s, 2, 64);
    float p = (j < KTOP) ? __expf(s * scale) : 0.f;
    if ((sl & 3) == 0 && j < KTOP) psh[j * 9 + h] = p;
    U4 vv;
    vv.u = *(const uint4*)(vbC + off);
    a8[0] += p * (float)vv.h[0][0]; a8[1] += p * (float)vv.h[0][1];
    a8[2] += p * (float)vv.h[1][0]; a8[3] += p * (float)vv.h[1][1];
    a8[4] += p * (float)vv.h[2][0]; a8[5] += p * (float)vv.h[2][1];
    a8[6] += p * (float)vv.h[3][0]; a8[7] += p * (float)vv.h[3][1];
  }
  __syncthreads();

  // per-head denominators
  {
    int h2 = tid >> 5, l = tid & 31;
    float sden = 0.f;
    for (int j = l; j < KTOP; j += 32) sden += psh[j * 9 + h2];
#pragma unroll
    for (int off = 16; off > 0; off >>= 1) sden += __shfl_down(sden, off, 32);
    if (l == 0) idsh[h2] = 1.0f / sden;
  }
  __syncthreads();

  // head-averaged normalized probs -> scatter into the dense row
  if (tid < KTOP) {
    float ps = 0.f;
#pragma unroll
    for (int hh = 0; hh < 8; ++hh) ps += psh[tid * 9 + hh] * idsh[hh];
    rcsh[ish[tid]] = ps * 0.125f;
  }
  __syncthreads();

  // stream dense row out (full-line, conflict-free)
  {
    float* arow = attn + (size_t)row * SEQ;
    *(float4*)(arow + tid * 4)        = *(const float4*)&rcsh[tid * 4];
    *(float4*)(arow + 1024 + tid * 4) = *(const float4*)&rcsh[1024 + tid * 4];
  }
  __syncthreads();   // rsh dead; csh may now overwrite the region

  // normalize context partials (late 1/den) and reduce across wave-halves
  {
    const float sc = idsh[h];
    const int pi = wv * 2 + half;
    *(float4*)&CSH(pi, d0)     = make_float4(a8[0]*sc, a8[1]*sc, a8[2]*sc, a8[3]*sc);
    *(float4*)&CSH(pi, d0 + 4) = make_float4(a8[4]*sc, a8[5]*sc, a8[6]*sc, a8[7]*sc);
  }
  __syncthreads();
  if (tid < 64) {
    float4 o = z4;
#pragma unroll
    for (int g = 0; g < 8; ++g) {
      float4 v = *(const float4*)&CSH(g, tid * 4);
      o.x += v.x; o.y += v.y; o.z += v.z; o.w += v.w;
    }
    *(float4*)(ctxb + (size_t)row * EMB + tid * 4) = o;
  }
#undef CSH
}

// ---------------------------------------------------------------------------
extern "C" void kernel_launch(void* const* d_in, const int* in_sizes, int n_in,
                              void* d_out, int out_size, void* d_ws, size_t ws_size,
                              hipStream_t stream)
{
  const float* x  = (const float*)d_in[0];
  const float* Wq = (const float*)d_in[1];
  const float* bq = (const float*)d_in[2];
  const float* Wk = (const float*)d_in[3];
  const float* bk = (const float*)d_in[4];
  const float* Wv = (const float*)d_in[5];
  const float* bv = (const float*)d_in[6];
  const float* Wo = (const float*)d_in[7];
  const float* bo = (const float*)d_in[8];

  float* out  = (float*)d_out;
  float* attn = out + (size_t)NB * SEQ * EMB;   // [B,S,S] region of d_out

  const size_t NSE = (size_t)NB * SEQ * EMB;    // 2097152
  u16* xh  = (u16*)d_ws;            // bf16 hi of x
  u16* xl  = xh + NSE;              // bf16 lo
  u16* qf  = xl + NSE;              // f16 Q
  u16* kf  = qf + NSE;              // f16 K
  u16* vf  = kf + NSE;              // f16 V
  u16* wpk = vf + NSE;              // 4 x (hi,lo) 256x256 bf16
  float* ctxb = (float*)(wpk + 4 * 2 * 65536);
  u16* idxl = (u16*)(ctxb + NSE);
  int* flagcnt  = (int*)(idxl + (size_t)NB * SEQ * IDXP);
  int* flaglist = flagcnt + NB;

  const dim3 blk(256);

  // hi/lo splits of x + weights (one launch); flag counters reset
  pack_all<<<dim3(1152), blk, 0, stream>>>(x, Wq, Wk, Wv, Wo, xh, xl, wpk, flagcnt);

  // symmetric scores (544 upper-triangle blocks) + QKV (384) in one launch
  // v9: global_load_lds staging
  fused_gemms<<<dim3(928), blk, 0, stream>>>(xh, xl, wpk, bq, bk, bv,
                                             qf, kf, vf, attn);

  // radix top-k with margin flagging; exact fp32 fixup of low-margin rows
  topk_idx<<<dim3(NB * SEQ), blk, 0, stream>>>(attn, idxl, flagcnt, flaglist);
  fixup_gemm<<<dim3(32, 32, NB), blk, 0, stream>>>(x, flagcnt, flaglist, attn);
  topk_fixup<<<dim3(SEQ, NB), blk, 0, stream>>>(attn, flagcnt, flaglist, idxl);

  // fused single-pass sparse attention (v8: 64-VGPR cap, unroll 2)
  sparse_attn<<<dim3(SEQ * NB), blk, 0, stream>>>(qf, kf, vf, idxl, attn, ctxb);

  // out = ctx @ Wo^T + bo (in-kernel hi/lo split of ctx)
  out_mfma<<<dim3(64, 2), blk, 0, stream>>>(ctxb, wpk, bo, out);
}

// Round 7
// 308.190 us; speedup vs baseline: 1.1364x; 1.0183x over previous
//
#include <hip/hip_runtime.h>

#define SEQ  2048
#define EMB  256
#define NH   8
#define HD   32
#define NB   4
#define KTOP 204
#define IDXP 208
#define KPW  52       // keys per wave (4*52 = 208, padded)
#define MBOUND 4e-4f  // top-k margin for fp32 re-verify

typedef unsigned long long ull;
typedef unsigned short u16;

using frag8  = __attribute__((ext_vector_type(8))) short;  // 8 bf16
using f32x4v = __attribute__((ext_vector_type(4))) float;
typedef _Float16 f16;
typedef _Float16 f16x2 __attribute__((ext_vector_type(2)));

union U4 { uint4 u; f16x2 h[4]; };
union HU { f16 h; u16 u; };

#if defined(__has_builtin)
#if __has_builtin(__builtin_amdgcn_fdot2)
#define FDOT2(a,b,c) __builtin_amdgcn_fdot2(a, b, c, false)
#endif
#endif
#ifndef FDOT2
__device__ __forceinline__ float fdot2_sw(f16x2 a, f16x2 b, float c) {
  return c + (float)a[0]*(float)b[0] + (float)a[1]*(float)b[1];
}
#define FDOT2(a,b,c) fdot2_sw(a,b,c)
#endif

__device__ __forceinline__ unsigned f2ord(float f) {
  unsigned u = __float_as_uint(f);
  return (u & 0x80000000u) ? ~u : (u | 0x80000000u);
}
__device__ __forceinline__ float ord2f(unsigned o) {
  unsigned u = (o & 0x80000000u) ? (o ^ 0x80000000u) : ~o;
  return __uint_as_float(u);
}
__device__ __forceinline__ u16 f2bf(float f) {
  unsigned u = __float_as_uint(f);
  u += 0x7FFF + ((u >> 16) & 1);     // RTNE
  return (u16)(u >> 16);
}
__device__ __forceinline__ float bf2f(u16 h) {
  return __uint_as_float((unsigned)h << 16);
}

// ---------------------------------------------------------------------------
// Async staging of one 128x32 bf16 tile via global_load_lds (width 16).
// LDS layout is LINEAR in slot S (16B each); the fragment-layout permutation
// is folded into the per-lane GLOBAL source address (swizzle-both-sides):
//   slot S holds (row = S>>2, quad = (S&3) ^ ((S>>3)&3)).
// Fragment read address: row*32 + (quad ^ ((row>>1)&3))*8  (u16 units).
// ---------------------------------------------------------------------------
__device__ __forceinline__ void stage128x32(
    const u16* __restrict__ src, int row0, int k0, u16* lds, int wv, int ln)
{
#pragma unroll
  for (int i = 0; i < 2; ++i) {
    const int S = wv * 128 + i * 64 + ln;
    const int row = S >> 2;
    const int q = (S & 3) ^ ((S >> 3) & 3);
    const u16* g = src + (size_t)(row0 + row) * EMB + k0 + q * 8;
    __builtin_amdgcn_global_load_lds(
        (const __attribute__((address_space(1))) unsigned*)g,
        (__attribute__((address_space(3))) unsigned*)(lds + (size_t)(S - ln) * 8),
        16, 0, 0);
  }
}

// ---------------------------------------------------------------------------
// Radix-256 top-k (4 byte passes, per-wave histograms, wave-0 suffix scan).
// v10 barrier diet: selection sums the 4 per-wave hists directly (combine
// step + its barrier removed); trailing second barrier removed (sel reads
// are protected by the next pass's zero+barrier before wave0 rewrites sel).
// ---------------------------------------------------------------------------
__device__ __forceinline__ void tk_radix(
    const unsigned key[8], int tid, int (*hist)[256], int* sel,
    unsigned& V, int& MEQ)
{
  const int lane = tid & 63, wid = tid >> 6;
  unsigned prefix = 0;
  int k = KTOP;
#pragma unroll
  for (int p = 0; p < 4; ++p) {
    const int shift = 24 - 8 * p;
    hist[0][tid] = 0; hist[1][tid] = 0; hist[2][tid] = 0; hist[3][tid] = 0;
    __syncthreads();
#pragma unroll
    for (int j = 0; j < 8; ++j) {
      unsigned kj = key[j];
      bool ok = (p == 0) || ((kj >> (shift + 8)) == prefix);
      if (ok) atomicAdd(&hist[wid][(kj >> shift) & 255], 1);
    }
    __syncthreads();
    if (wid == 0) {
      const int b0 = lane * 4;
      int m0 = hist[0][b0+0] + hist[1][b0+0] + hist[2][b0+0] + hist[3][b0+0];
      int m1 = hist[0][b0+1] + hist[1][b0+1] + hist[2][b0+1] + hist[3][b0+1];
      int m2 = hist[0][b0+2] + hist[1][b0+2] + hist[2][b0+2] + hist[3][b0+2];
      int m3 = hist[0][b0+3] + hist[1][b0+3] + hist[2][b0+3] + hist[3][b0+3];
      int sl = m0 + m1 + m2 + m3;
      int suf = sl;
#pragma unroll
      for (int off = 1; off < 64; off <<= 1) {
        int y = __shfl_down(suf, off, 64);
        if (lane + off < 64) suf += y;
      }
      int above = suf - sl;
      if (above < k && k <= suf) {
        int bin, nk;
        if (k <= above + m3)                { bin = b0+3; nk = k - above; }
        else if (k <= above + m3 + m2)      { bin = b0+2; nk = k - above - m3; }
        else if (k <= above + m3 + m2 + m1) { bin = b0+1; nk = k - above - m3 - m2; }
        else                                { bin = b0+0; nk = k - above - m3 - m2 - m1; }
        sel[0] = bin; sel[1] = nk;
      }
    }
    __syncthreads();
    prefix = (prefix << 8) | (unsigned)sel[0];
    k = sel[1];
    // second trailing barrier removed (see header comment)
  }
  V = prefix;
  MEQ = k;
}

__device__ __forceinline__ int tk_scan_excl(int v, int tid, int* wsum) {
  const int lane = tid & 63, wid = tid >> 6;
  int x = v;
#pragma unroll
  for (int off = 1; off < 64; off <<= 1) {
    int y = __shfl_up(x, off, 64);
    if (lane >= off) x += y;
  }
  if (lane == 63) wsum[wid] = x;
  __syncthreads();
  int base = 0;
  for (int w = 0; w < wid; ++w) base += wsum[w];
  return base + x - v;
}

__device__ __forceinline__ void tk_write(const unsigned key[8], unsigned V, int MEQ,
                                         int tid, u16* orow, int* wsum) {
  int ceq = 0;
#pragma unroll
  for (int j = 0; j < 8; ++j) ceq += (key[j] == V) ? 1 : 0;
  int run = tk_scan_excl(ceq, tid, wsum);
  unsigned bits = 0;
#pragma unroll
  for (int j = 0; j < 8; ++j) {
    bool e = (key[j] == V);
    bool s = (key[j] > V) || (e && (run < MEQ));
    if (e) run++;
    if (s) bits |= (1u << j);
  }
  int csel = __popc(bits);
  __syncthreads();
  int base = tk_scan_excl(csel, tid, wsum);
#pragma unroll
  for (int j = 0; j < 8; ++j)
    if ((bits >> j) & 1u) orow[base++] = (u16)(tid * 8 + j);
}

// ---------------------------------------------------------------------------
// pack_all: bf16 hi/lo split of x (blocks 0..1023) and the 4 weight matrices
// (blocks 1024..1151); block 0 also zeroes the per-batch flag counters.
// ---------------------------------------------------------------------------
__global__ __launch_bounds__(256) void pack_all(
    const float* __restrict__ x,
    const float* __restrict__ W0, const float* __restrict__ W1,
    const float* __restrict__ W2, const float* __restrict__ W3,
    u16* __restrict__ xh, u16* __restrict__ xl, u16* __restrict__ wpk,
    int* __restrict__ flagcnt)
{
  const int lin = blockIdx.x;
  if (lin == 0 && threadIdx.x < NB) flagcnt[threadIdx.x] = 0;
  const float* src; u16 *dh, *dl; int i;
  if (lin < 1024) {
    src = x;
    i = (lin * 256 + threadIdx.x) * 8;
    dh = xh; dl = xl;
  } else {
    int j = lin - 1024;             // 0..127
    int m = j >> 5, bx = j & 31;
    src = (m == 0) ? W0 : (m == 1) ? W1 : (m == 2) ? W2 : W3;
    i = (bx * 256 + threadIdx.x) * 8;
    dh = wpk + (size_t)m * 2 * 65536;
    dl = dh + 65536;
  }
  float4 a = *(const float4*)(src + i);
  float4 b = *(const float4*)(src + i + 4);
  float v[8] = {a.x,a.y,a.z,a.w,b.x,b.y,b.z,b.w};
  u16 h[8], l[8];
#pragma unroll
  for (int j = 0; j < 8; ++j) {
    h[j] = f2bf(v[j]);
    l[j] = f2bf(v[j] - bf2f(h[j]));
  }
  uint4 ph, pl;
  ph.x = h[0] | ((unsigned)h[1] << 16); ph.y = h[2] | ((unsigned)h[3] << 16);
  ph.z = h[4] | ((unsigned)h[5] << 16); ph.w = h[6] | ((unsigned)h[7] << 16);
  pl.x = l[0] | ((unsigned)l[1] << 16); pl.y = l[2] | ((unsigned)l[3] << 16);
  pl.z = l[4] | ((unsigned)l[5] << 16); pl.w = l[6] | ((unsigned)l[7] << 16);
  *(uint4*)(dh + i) = ph;
  *(uint4*)(dl + i) = pl;
}

// ---------------------------------------------------------------------------
// fused_gemms: scores (SYMMETRIC — upper-triangle blocks only, mirror written
// from registers; blocks 0..543) + QKV projections (blocks 544..927).
// v9 staging: global_load_lds width-16, linear LDS, source-side permutation.
// Scores use 3-term hi/lo MFMA (lo*lo dropped; error ~3e-6 << MBOUND).
// ---------------------------------------------------------------------------
__global__ __launch_bounds__(256) void fused_gemms(
    const u16* __restrict__ xh, const u16* __restrict__ xl,
    const u16* __restrict__ wpk,
    const float* __restrict__ bq, const float* __restrict__ bk,
    const float* __restrict__ bv,
    u16* __restrict__ qo, u16* __restrict__ ko, u16* __restrict__ vo,
    float* __restrict__ attnC)
{
  __shared__ u16 Ah[128 * 32], Al[128 * 32], Bh[128 * 32], Bl[128 * 32];
  const int lin = blockIdx.x;
  const int tid = threadIdx.x;
  const int wv = tid >> 6, ln = tid & 63;
  const int quad = ln >> 4, r16 = ln & 15;
  const int perm = quad ^ ((r16 >> 1) & 3);     // read-side swizzle (matches stage)
  const int wm = (wv & 1) * 64, wn = (wv >> 1) * 64;

  f32x4v acc[4][4];
#pragma unroll
  for (int i = 0; i < 4; ++i)
#pragma unroll
    for (int j = 0; j < 4; ++j) acc[i][j] = (f32x4v){0.f, 0.f, 0.f, 0.f};

  if (lin < 544) {
    // ----- scores path (symmetric, bi <= bj) -----
    const int b = lin / 136;
    int p = lin - b * 136;
    int bi = 0;
    while (p >= 16 - bi) { p -= 16 - bi; ++bi; }
    const int bj = bi + p;
    const int m0 = bi * 128, n0 = bj * 128;
    const u16* xhB = xh + (size_t)b * SEQ * EMB;
    const u16* xlB = xl + (size_t)b * SEQ * EMB;
    float* Cb = attnC + (size_t)b * SEQ * SEQ;
    for (int k0 = 0; k0 < EMB; k0 += 32) {
      __syncthreads();
      stage128x32(xhB, m0, k0, Ah, wv, ln);
      stage128x32(xlB, m0, k0, Al, wv, ln);
      stage128x32(xhB, n0, k0, Bh, wv, ln);
      stage128x32(xlB, n0, k0, Bl, wv, ln);
      __syncthreads();
      frag8 fbh[4], fbl[4];
#pragma unroll
      for (int nt = 0; nt < 4; ++nt) {
        int ob = ((wn + nt * 16 + r16) << 5) + (perm << 3);
        fbh[nt] = *(const frag8*)&Bh[ob];
        fbl[nt] = *(const frag8*)&Bl[ob];
      }
#pragma unroll
      for (int mt = 0; mt < 4; ++mt) {
        int oa = ((wm + mt * 16 + r16) << 5) + (perm << 3);
        frag8 fah = *(const frag8*)&Ah[oa];
        frag8 fal = *(const frag8*)&Al[oa];
#pragma unroll
        for (int nt = 0; nt < 4; ++nt) {
          acc[mt][nt] = __builtin_amdgcn_mfma_f32_16x16x32_bf16(fah, fbh[nt], acc[mt][nt], 0, 0, 0);
          acc[mt][nt] = __builtin_amdgcn_mfma_f32_16x16x32_bf16(fah, fbl[nt], acc[mt][nt], 0, 0, 0);
          acc[mt][nt] = __builtin_amdgcn_mfma_f32_16x16x32_bf16(fal, fbh[nt], acc[mt][nt], 0, 0, 0);
        }
      }
    }
    // normal write (upper block)
#pragma unroll
    for (int mt = 0; mt < 4; ++mt)
#pragma unroll
      for (int nt = 0; nt < 4; ++nt) {
        int cg = n0 + wn + nt * 16 + r16;
        int rb = m0 + wm + mt * 16 + quad * 4;
#pragma unroll
        for (int r = 0; r < 4; ++r)
          Cb[(size_t)(rb + r) * SEQ + cg] = acc[mt][nt][r] * 0.0625f;
      }
    // mirror write (lower block): element (rb+r, cg) -> (cg, rb+r).
    if (bi != bj) {
#pragma unroll
      for (int mt = 0; mt < 4; ++mt)
#pragma unroll
        for (int nt = 0; nt < 4; ++nt) {
          int cg = n0 + wn + nt * 16 + r16;
          int rb = m0 + wm + mt * 16 + quad * 4;
          float4 o;
          o.x = acc[mt][nt][0] * 0.0625f;
          o.y = acc[mt][nt][1] * 0.0625f;
          o.z = acc[mt][nt][2] * 0.0625f;
          o.w = acc[mt][nt][3] * 0.0625f;
          *(float4*)&Cb[(size_t)cg * SEQ + rb] = o;
        }
    }
  } else {
    // ----- qkv path -----
    const int j = lin - 544;
    const int m0 = (j & 63) * 128, n0 = ((j >> 6) & 1) * 128;
    const int z = j >> 7;
    const u16* Wh = wpk + (size_t)z * 2 * 65536;
    const u16* Wl = Wh + 65536;
    const float* bias = (z == 0) ? bq : (z == 1) ? bk : bv;
    u16* out = (z == 0) ? qo : (z == 1) ? ko : vo;
    for (int k0 = 0; k0 < EMB; k0 += 32) {
      __syncthreads();
      stage128x32(xh, m0, k0, Ah, wv, ln);
      stage128x32(xl, m0, k0, Al, wv, ln);
      stage128x32(Wh, n0, k0, Bh, wv, ln);
      stage128x32(Wl, n0, k0, Bl, wv, ln);
      __syncthreads();
      frag8 fbh[4], fbl[4];
#pragma unroll
      for (int nt = 0; nt < 4; ++nt) {
        int ob = ((wn + nt * 16 + r16) << 5) + (perm << 3);
        fbh[nt] = *(const frag8*)&Bh[ob];
        fbl[nt] = *(const frag8*)&Bl[ob];
      }
#pragma unroll
      for (int mt = 0; mt < 4; ++mt) {
        int oa = ((wm + mt * 16 + r16) << 5) + (perm << 3);
        frag8 fah = *(const frag8*)&Ah[oa];
        frag8 fal = *(const frag8*)&Al[oa];
#pragma unroll
        for (int nt = 0; nt < 4; ++nt) {
          acc[mt][nt] = __builtin_amdgcn_mfma_f32_16x16x32_bf16(fah, fbh[nt], acc[mt][nt], 0, 0, 0);
          acc[mt][nt] = __builtin_amdgcn_mfma_f32_16x16x32_bf16(fah, fbl[nt], acc[mt][nt], 0, 0, 0);
          acc[mt][nt] = __builtin_amdgcn_mfma_f32_16x16x32_bf16(fal, fbh[nt], acc[mt][nt], 0, 0, 0);
        }
      }
    }
#pragma unroll
    for (int nt = 0; nt < 4; ++nt) {
      int cg = n0 + wn + nt * 16 + r16;
      float bvv = bias[cg];
#pragma unroll
      for (int mt = 0; mt < 4; ++mt) {
        int rb = m0 + wm + mt * 16 + quad * 4;
#pragma unroll
        for (int r = 0; r < 4; ++r) {
          HU hu; hu.h = (f16)(acc[mt][nt][r] + bvv);
          out[(size_t)(rb + r) * EMB + cg] = hu.u;
        }
      }
    }
  }
}

// ---------------------------------------------------------------------------
// Out projection v10: tile 64x128 (was 128x128) -> grid 256 blocks fills all
// 256 CUs (was 128 = half idle). Waves 1x4 (wn=wv*32), acc[4][2]. Same MFMA
// terms and rounding path -> bit-identical numerics. Stride-40 LDS kept.
// ---------------------------------------------------------------------------
__global__ __launch_bounds__(256) void out_mfma(
    const float* __restrict__ ctx, const u16* __restrict__ wpk,
    const float* __restrict__ bias, float* __restrict__ out)
{
  const u16* Wh = wpk + (size_t)3 * 2 * 65536;
  const u16* Wl = Wh + 65536;
  __shared__ u16 Ah[64 * 40], Al[64 * 40], Bh[128 * 40], Bl[128 * 40];
  const int tid = threadIdx.x;
  const int m0 = blockIdx.x * 64, n0 = blockIdx.y * 128;
  const int wv = tid >> 6, ln = tid & 63;
  const int quad = ln >> 4, r16 = ln & 15;
  const int wn = wv * 32;
  const int arow = tid >> 2, acol = (tid & 3) * 8;   // A staging: 64 rows x 32 cols
  const int srow = tid >> 1, shalf = (tid & 1) * 16; // B staging: 128 rows

  f32x4v acc[4][2];
#pragma unroll
  for (int i = 0; i < 4; ++i)
#pragma unroll
    for (int j = 0; j < 2; ++j) acc[i][j] = (f32x4v){0.f, 0.f, 0.f, 0.f};

  for (int k0 = 0; k0 < EMB; k0 += 32) {
    __syncthreads();
    {
      // A: ctx fp32 -> hi/lo split, 8 values per thread
      size_t ga = (size_t)(m0 + arow) * EMB + k0 + acol;
      float4 c0 = *(const float4*)(ctx + ga);
      float4 c1 = *(const float4*)(ctx + ga + 4);
      float v[8] = {c0.x,c0.y,c0.z,c0.w, c1.x,c1.y,c1.z,c1.w};
      u16 hh[8], ll[8];
#pragma unroll
      for (int jj = 0; jj < 8; ++jj) {
        hh[jj] = f2bf(v[jj]);
        ll[jj] = f2bf(v[jj] - bf2f(hh[jj]));
      }
      uint4 ph, pl;
      ph.x = hh[0] | ((unsigned)hh[1] << 16); ph.y = hh[2] | ((unsigned)hh[3] << 16);
      ph.z = hh[4] | ((unsigned)hh[5] << 16); ph.w = hh[6] | ((unsigned)hh[7] << 16);
      pl.x = ll[0] | ((unsigned)ll[1] << 16); pl.y = ll[2] | ((unsigned)ll[3] << 16);
      pl.z = ll[4] | ((unsigned)ll[5] << 16); pl.w = ll[6] | ((unsigned)ll[7] << 16);
      int oA = arow * 40 + acol;
      *(uint4*)&Ah[oA] = ph;
      *(uint4*)&Al[oA] = pl;
      // B: Wo hi/lo bf16 loads
      size_t gb = (size_t)(n0 + srow) * EMB + k0 + shalf;
      uint4 bh0 = *(const uint4*)(Wh + gb), bh1 = *(const uint4*)(Wh + gb + 8);
      uint4 bl0 = *(const uint4*)(Wl + gb), bl1 = *(const uint4*)(Wl + gb + 8);
      int oB = srow * 40 + shalf;
      *(uint4*)&Bh[oB] = bh0; *(uint4*)&Bh[oB + 8] = bh1;
      *(uint4*)&Bl[oB] = bl0; *(uint4*)&Bl[oB + 8] = bl1;
    }
    __syncthreads();
    frag8 fbh[2], fbl[2];
#pragma unroll
    for (int nt = 0; nt < 2; ++nt) {
      int ob = (wn + nt * 16 + r16) * 40 + quad * 8;
      fbh[nt] = *(const frag8*)&Bh[ob];
      fbl[nt] = *(const frag8*)&Bl[ob];
    }
#pragma unroll
    for (int mt = 0; mt < 4; ++mt) {
      int oa = (mt * 16 + r16) * 40 + quad * 8;
      frag8 fah = *(const frag8*)&Ah[oa];
      frag8 fal = *(const frag8*)&Al[oa];
#pragma unroll
      for (int nt = 0; nt < 2; ++nt) {
        acc[mt][nt] = __builtin_amdgcn_mfma_f32_16x16x32_bf16(fah, fbh[nt], acc[mt][nt], 0, 0, 0);
        acc[mt][nt] = __builtin_amdgcn_mfma_f32_16x16x32_bf16(fah, fbl[nt], acc[mt][nt], 0, 0, 0);
        acc[mt][nt] = __builtin_amdgcn_mfma_f32_16x16x32_bf16(fal, fbh[nt], acc[mt][nt], 0, 0, 0);
      }
    }
  }
#pragma unroll
  for (int nt = 0; nt < 2; ++nt) {
    int cg = n0 + wn + nt * 16 + r16;
    float bvv = bias[cg];
#pragma unroll
    for (int mt = 0; mt < 4; ++mt) {
      int rb = m0 + mt * 16 + quad * 4;
#pragma unroll
      for (int r = 0; r < 4; ++r)
        out[(size_t)(rb + r) * EMB + cg] = acc[mt][nt][r] + bvv;
    }
  }
}

// ---------------------------------------------------------------------------
// Top-k per row (radix-256), with margin flagging into per-batch lists.
// ---------------------------------------------------------------------------
__global__ __launch_bounds__(256) void topk_idx(
    const float* __restrict__ scores, u16* __restrict__ idxl,
    int* __restrict__ flagcnt, int* __restrict__ flaglist)
{
  __shared__ int hist[4][256];
  __shared__ int sel[2];
  __shared__ int wsum[4];
  __shared__ unsigned wmax[4];
  const int r = blockIdx.x;
  const int tid = threadIdx.x;
  const int lane = tid & 63, wid = tid >> 6;
  const float* row = scores + (size_t)r * SEQ;
  unsigned key[8];
  {
    float4 f0 = *(const float4*)(row + tid * 8);
    float4 f1 = *(const float4*)(row + tid * 8 + 4);
    key[0]=f2ord(f0.x); key[1]=f2ord(f0.y); key[2]=f2ord(f0.z); key[3]=f2ord(f0.w);
    key[4]=f2ord(f1.x); key[5]=f2ord(f1.y); key[6]=f2ord(f1.z); key[7]=f2ord(f1.w);
  }
  unsigned V; int MEQ;
  tk_radix(key, tid, hist, sel, V, MEQ);

  {
    int ceq = 0; unsigned mk = 0;
#pragma unroll
    for (int j = 0; j < 8; ++j) {
      ceq += (key[j] == V) ? 1 : 0;
      if (key[j] < V && key[j] > mk) mk = key[j];
    }
#pragma unroll
    for (int off = 32; off > 0; off >>= 1) {
      ceq += __shfl_down(ceq, off, 64);
      unsigned o = (unsigned)__shfl_down((int)mk, off, 64);
      if (o > mk) mk = o;
    }
    if (lane == 0) { wsum[wid] = ceq; wmax[wid] = mk; }
    __syncthreads();
    if (tid == 0) {
      int EQ = wsum[0] + wsum[1] + wsum[2] + wsum[3];
      unsigned m2 = wmax[0];
      for (int w = 1; w < 4; ++w) if (wmax[w] > m2) m2 = wmax[w];
      bool flag = (EQ > MEQ) || !(ord2f(V) - ord2f(m2) >= MBOUND);
      if (flag) {
        int bb = r >> 11;
        int p = atomicAdd(&flagcnt[bb], 1);
        flaglist[bb * SEQ + p] = r & (SEQ - 1);
      }
    }
    __syncthreads();
  }

  tk_write(key, V, MEQ, tid, idxl + (size_t)r * IDXP, wsum);
}

// ---------------------------------------------------------------------------
// Fixup A: exact fp32 scores for flagged rows (gathered-A 64x64 GEMM).
// ---------------------------------------------------------------------------
__global__ __launch_bounds__(256) void fixup_gemm(
    const float* __restrict__ x, const int* __restrict__ flagcnt,
    const int* __restrict__ flaglist, float* __restrict__ attn)
{
  const int b = blockIdx.z;
  const int n = flagcnt[b];
  const int g0 = blockIdx.y * 64;
  if (g0 >= n) return;
  __shared__ float As[16][68];
  __shared__ float Bs[16][68];
  __shared__ int rowsh[64];
  const int tid = threadIdx.x;
  const int n0 = blockIdx.x * 64;
  if (tid < 64) {
    int gi = g0 + tid;
    rowsh[tid] = (gi < n) ? flaglist[b * SEQ + gi] : -1;
  }
  __syncthreads();
  const float* xb = x + (size_t)b * SEQ * EMB;
  const int lm = tid >> 2;
  const int lk = (tid & 3) << 2;
  const int mt = tid >> 4;
  const int nt = tid & 15;
  const int arow = rowsh[lm];
  const int arowL = (arow < 0) ? 0 : arow;
  float acc[4][4] = {{0.f}};
  for (int k0 = 0; k0 < EMB; k0 += 16) {
    float4 av = *(const float4*)(xb + (size_t)arowL * EMB + k0 + lk);
    float4 bv = *(const float4*)(xb + (size_t)(n0 + lm) * EMB + k0 + lk);
    __syncthreads();
    As[lk+0][lm] = av.x; As[lk+1][lm] = av.y; As[lk+2][lm] = av.z; As[lk+3][lm] = av.w;
    Bs[lk+0][lm] = bv.x; Bs[lk+1][lm] = bv.y; Bs[lk+2][lm] = bv.z; Bs[lk+3][lm] = bv.w;
    __syncthreads();
#pragma unroll
    for (int kk = 0; kk < 16; ++kk) {
      float4 a4 = *(const float4*)&As[kk][mt << 2];
      float4 b4 = *(const float4*)&Bs[kk][nt << 2];
      acc[0][0] += a4.x*b4.x; acc[0][1] += a4.x*b4.y; acc[0][2] += a4.x*b4.z; acc[0][3] += a4.x*b4.w;
      acc[1][0] += a4.y*b4.x; acc[1][1] += a4.y*b4.y; acc[1][2] += a4.y*b4.z; acc[1][3] += a4.y*b4.w;
      acc[2][0] += a4.z*b4.x; acc[2][1] += a4.z*b4.y; acc[2][2] += a4.z*b4.z; acc[2][3] += a4.z*b4.w;
      acc[3][0] += a4.w*b4.x; acc[3][1] += a4.w*b4.y; acc[3][2] += a4.w*b4.z; acc[3][3] += a4.w*b4.w;
    }
  }
  float* attnB = attn + (size_t)b * SEQ * SEQ;
#pragma unroll
  for (int r = 0; r < 4; ++r) {
    int rr = rowsh[(mt << 2) + r];
    if (rr >= 0) {
      float4 o;
      o.x = acc[r][0] * 0.0625f; o.y = acc[r][1] * 0.0625f;
      o.z = acc[r][2] * 0.0625f; o.w = acc[r][3] * 0.0625f;
      *(float4*)(attnB + (size_t)rr * SEQ + n0 + (nt << 2)) = o;
    }
  }
}

// ---------------------------------------------------------------------------
// Fixup B: redo top-k (radix) on the now-exact flagged rows.
// ---------------------------------------------------------------------------
__global__ __launch_bounds__(256) void topk_fixup(
    const float* __restrict__ attn, const int* __restrict__ flagcnt,
    const int* __restrict__ flaglist, u16* __restrict__ idxl)
{
  const int b = blockIdx.y;
  if ((int)blockIdx.x >= flagcnt[b]) return;
  const int r = b * SEQ + flaglist[b * SEQ + blockIdx.x];
  __shared__ int hist[4][256];
  __shared__ int sel[2];
  __shared__ int wsum[4];
  const int tid = threadIdx.x;
  const float* row = attn + (size_t)r * SEQ;
  unsigned key[8];
  {
    float4 f0 = *(const float4*)(row + tid * 8);
    float4 f1 = *(const float4*)(row + tid * 8 + 4);
    key[0]=f2ord(f0.x); key[1]=f2ord(f0.y); key[2]=f2ord(f0.z); key[3]=f2ord(f0.w);
    key[4]=f2ord(f1.x); key[5]=f2ord(f1.y); key[6]=f2ord(f1.z); key[7]=f2ord(f1.w);
  }
  unsigned V; int MEQ;
  tk_radix(key, tid, hist, sel, V, MEQ);
  tk_write(key, V, MEQ, tid, idxl + (size_t)r * IDXP, wsum);
}

// ---------------------------------------------------------------------------
// Sparse attention v8 (kept): fused single pass at 24 VGPR / ~75% occupancy.
// R5/R6 measured it at the scattered-L2 gather roofline (~20.5 TB/s of 34.5
// ceiling; gather bytes already minimal) — do not push further.
// ---------------------------------------------------------------------------
__global__ __launch_bounds__(256, 8) void sparse_attn(
    const u16* __restrict__ qf, const u16* __restrict__ kf,
    const u16* __restrict__ vf, const u16* __restrict__ idxl,
    float* __restrict__ attn, float* __restrict__ ctxb)
{
  const int lin = blockIdx.x;
  const int b = lin & 3;                                  // XCD-stable batch
  const int q = (lin >> 3) + (((lin >> 2) & 1) << 10);
  const int tid = threadIdx.x;
  const int wv = tid >> 6, ln = tid & 63;
  const int half = ln >> 5, sl = ln & 31;
  const int h = sl >> 2, d0 = sl * 8;
  const int lb = sl * 16;
  __shared__ int   ish[IDXP];
  __shared__ int   koff[IDXP];
  __shared__ float psh[IDXP * 9 + 4];   // [j][h], stride 9 (raw exp, unnormalized)
  __shared__ float idsh[NH];
  __shared__ float rcsh[2112];          // union: rsh[2048] | csh[8][264]
#define CSH(i, j) rcsh[(i) * 264 + (j)]

  const int row = b * SEQ + q;
  if (tid < KTOP) {
    int idx = (int)idxl[(size_t)row * IDXP + tid];
    ish[tid] = idx;
    koff[tid] = idx << 9;
  } else if (tid < IDXP) {
    ish[tid] = 0; koff[tid] = 0;
  }

  float4 z4 = make_float4(0.f, 0.f, 0.f, 0.f);
  *(float4*)&rcsh[tid * 4]        = z4;
  *(float4*)&rcsh[1024 + tid * 4] = z4;

  U4 qv;
  qv.u = *(const uint4*)((const char*)(qf + (size_t)row * EMB) + lb);

  __syncthreads();

  const float scale = 0.17677669529663687f;  // 1/sqrt(32)
  const char* kbC = (const char*)(kf + (size_t)(b * SEQ) * EMB);
  const char* vbC = (const char*)(vf + (size_t)(b * SEQ) * EMB);
  const int jb = wv * KPW;
  float a8[8] = {0.f,0.f,0.f,0.f,0.f,0.f,0.f,0.f};
#pragma unroll 2
  for (int t = 0; t < KPW; t += 2) {
    const int j = jb + t + half;
    const int off = koff[j] + lb;
    U4 kv;
    kv.u = *(const uint4*)(kbC + off);
    float s = FDOT2(qv.h[0], kv.h[0],
              FDOT2(qv.h[1], kv.h[1],
              FDOT2(qv.h[2], kv.h[2],
              FDOT2(qv.h[3], kv.h[3], 0.f))));
    s += __shfl_xor(s, 1, 64);
    s += __shfl_xor(s, 2, 64);
    float p = (j < KTOP) ? __expf(s * scale) : 0.f;
    if ((sl & 3) == 0 && j < KTOP) psh[j * 9 + h] = p;
    U4 vv;
    vv.u = *(const uint4*)(vbC + off);
    a8[0] += p * (float)vv.h[0][0]; a8[1] += p * (float)vv.h[0][1];
    a8[2] += p * (float)vv.h[1][0]; a8[3] += p * (float)vv.h[1][1];
    a8[4] += p * (float)vv.h[2][0]; a8[5] += p * (float)vv.h[2][1];
    a8[6] += p * (float)vv.h[3][0]; a8[7] += p * (float)vv.h[3][1];
  }
  __syncthreads();

  // per-head denominators
  {
    int h2 = tid >> 5, l = tid & 31;
    float sden = 0.f;
    for (int j = l; j < KTOP; j += 32) sden += psh[j * 9 + h2];
#pragma unroll
    for (int off = 16; off > 0; off >>= 1) sden += __shfl_down(sden, off, 32);
    if (l == 0) idsh[h2] = 1.0f / sden;
  }
  __syncthreads();

  // head-averaged normalized probs -> scatter into the dense row
  if (tid < KTOP) {
    float ps = 0.f;
#pragma unroll
    for (int hh = 0; hh < 8; ++hh) ps += psh[tid * 9 + hh] * idsh[hh];
    rcsh[ish[tid]] = ps * 0.125f;
  }
  __syncthreads();

  // stream dense row out (full-line, conflict-free)
  {
    float* arow = attn + (size_t)row * SEQ;
    *(float4*)(arow + tid * 4)        = *(const float4*)&rcsh[tid * 4];
    *(float4*)(arow + 1024 + tid * 4) = *(const float4*)&rcsh[1024 + tid * 4];
  }
  __syncthreads();   // rsh dead; csh may now overwrite the region

  // normalize context partials (late 1/den) and reduce across wave-halves
  {
    const float sc = idsh[h];
    const int pi = wv * 2 + half;
    *(float4*)&CSH(pi, d0)     = make_float4(a8[0]*sc, a8[1]*sc, a8[2]*sc, a8[3]*sc);
    *(float4*)&CSH(pi, d0 + 4) = make_float4(a8[4]*sc, a8[5]*sc, a8[6]*sc, a8[7]*sc);
  }
  __syncthreads();
  if (tid < 64) {
    float4 o = z4;
#pragma unroll
    for (int g = 0; g < 8; ++g) {
      float4 v = *(const float4*)&CSH(g, tid * 4);
      o.x += v.x; o.y += v.y; o.z += v.z; o.w += v.w;
    }
    *(float4*)(ctxb + (size_t)row * EMB + tid * 4) = o;
  }
#undef CSH
}

// ---------------------------------------------------------------------------
extern "C" void kernel_launch(void* const* d_in, const int* in_sizes, int n_in,
                              void* d_out, int out_size, void* d_ws, size_t ws_size,
                              hipStream_t stream)
{
  const float* x  = (const float*)d_in[0];
  const float* Wq = (const float*)d_in[1];
  const float* bq = (const float*)d_in[2];
  const float* Wk = (const float*)d_in[3];
  const float* bk = (const float*)d_in[4];
  const float* Wv = (const float*)d_in[5];
  const float* bv = (const float*)d_in[6];
  const float* Wo = (const float*)d_in[7];
  const float* bo = (const float*)d_in[8];

  float* out  = (float*)d_out;
  float* attn = out + (size_t)NB * SEQ * EMB;   // [B,S,S] region of d_out

  const size_t NSE = (size_t)NB * SEQ * EMB;    // 2097152
  u16* xh  = (u16*)d_ws;            // bf16 hi of x
  u16* xl  = xh + NSE;              // bf16 lo
  u16* qf  = xl + NSE;              // f16 Q
  u16* kf  = qf + NSE;              // f16 K
  u16* vf  = kf + NSE;              // f16 V
  u16* wpk = vf + NSE;              // 4 x (hi,lo) 256x256 bf16
  float* ctxb = (float*)(wpk + 4 * 2 * 65536);
  u16* idxl = (u16*)(ctxb + NSE);
  int* flagcnt  = (int*)(idxl + (size_t)NB * SEQ * IDXP);
  int* flaglist = flagcnt + NB;

  const dim3 blk(256);

  // hi/lo splits of x + weights (one launch); flag counters reset
  pack_all<<<dim3(1152), blk, 0, stream>>>(x, Wq, Wk, Wv, Wo, xh, xl, wpk, flagcnt);

  // symmetric scores (544 upper-triangle blocks) + QKV (384) in one launch
  fused_gemms<<<dim3(928), blk, 0, stream>>>(xh, xl, wpk, bq, bk, bv,
                                             qf, kf, vf, attn);

  // radix top-k with margin flagging; exact fp32 fixup of low-margin rows
  topk_idx<<<dim3(NB * SEQ), blk, 0, stream>>>(attn, idxl, flagcnt, flaglist);
  fixup_gemm<<<dim3(32, 32, NB), blk, 0, stream>>>(x, flagcnt, flaglist, attn);
  topk_fixup<<<dim3(SEQ, NB), blk, 0, stream>>>(attn, flagcnt, flaglist, idxl);

  // fused single-pass sparse attention (v8: 64-VGPR cap, unroll 2)
  sparse_attn<<<dim3(SEQ * NB), blk, 0, stream>>>(qf, kf, vf, idxl, attn, ctxb);

  // out = ctx @ Wo^T + bo (v10: 256 blocks, 64x128 tiles)
  out_mfma<<<dim3(128, 2), blk, 0, stream>>>(ctxb, wpk, bo, out);
}